// Round 1
// baseline (694.266 us; speedup 1.0000x reference)
//
#include <hip/hip_runtime.h>
#include <hip/hip_bf16.h>
#include <math.h>

// Problem constants (b=2, s=2048, d=512, h=8, k=64, rounds=4, buckets=32, cs=64)
#define B_ 2
#define S_ 2048
#define D_ 512
#define H_ 8
#define K_ 64
#define R_ 4
#define NB_ 32
#define CS_ 64
#define WS_ 192          // 3 * CS_ (acn=1 window)
#define NEGF (-3.402823466e+38f)

// ---------------------------------------------------------------------------
// Generic f32 GEMM: C = A(M x 512) @ W(512 x 512) + bias, M = 4096.
// mode 0: write to (b,h,s,k) layout buffer ; mode 1: row-major direct.
// ---------------------------------------------------------------------------
__global__ __launch_bounds__(256) void gemm_bias(const float* __restrict__ A,
                                                 const float* __restrict__ W,
                                                 const float* __restrict__ bias,
                                                 float* __restrict__ C, int mode) {
    __shared__ float As[16][65];
    __shared__ float Ws[16][65];
    const int m0 = blockIdx.x * 64;
    const int n0 = blockIdx.y * 64;
    const int tid = threadIdx.x;
    const int ty = tid >> 4, tx = tid & 15;
    float acc[4][4] = {};
    for (int k0 = 0; k0 < 512; k0 += 16) {
        for (int l = tid; l < 64 * 16; l += 256) {
            int i = l >> 4, kk = l & 15;
            As[kk][i] = A[(size_t)(m0 + i) * 512 + k0 + kk];
        }
        for (int l = tid; l < 16 * 64; l += 256) {
            int kk = l >> 6, j = l & 63;
            Ws[kk][j] = W[(size_t)(k0 + kk) * 512 + n0 + j];
        }
        __syncthreads();
#pragma unroll
        for (int kk = 0; kk < 16; ++kk) {
            float a[4], w[4];
#pragma unroll
            for (int i = 0; i < 4; ++i) a[i] = As[kk][ty * 4 + i];
#pragma unroll
            for (int j = 0; j < 4; ++j) w[j] = Ws[kk][tx * 4 + j];
#pragma unroll
            for (int i = 0; i < 4; ++i)
#pragma unroll
                for (int j = 0; j < 4; ++j) acc[i][j] += a[i] * w[j];
        }
        __syncthreads();
    }
#pragma unroll
    for (int i = 0; i < 4; ++i) {
        int m = m0 + ty * 4 + i;
#pragma unroll
        for (int j = 0; j < 4; ++j) {
            int n = n0 + tx * 4 + j;
            float val = acc[i][j] + bias[n];
            if (mode == 0) {
                int b = m >> 11, s = m & 2047;
                int h = n >> 6, kk = n & 63;
                C[(size_t)(((b << 3) + h) * 2048 + s) * 64 + kk] = val;
            } else {
                C[(size_t)m * 512 + n] = val;
            }
        }
    }
}

// ---------------------------------------------------------------------------
// LSH hashing: per token compute rot[v=16][r=4], bucket[r] = argmax over 32
// of concat(-rot, rot), first-occurrence tie-break.  loc2[(token)*4 + r].
// ---------------------------------------------------------------------------
__global__ __launch_bounds__(256) void hash_kernel(const float* __restrict__ qk,
                                                   const float* __restrict__ hv,
                                                   int* __restrict__ loc2) {
    __shared__ float qs[4][64];
    __shared__ float rot[4][64];  // [tok][v*4+r]
    const int t0 = blockIdx.x * 4;            // global token base ((b*8+h)*2048+s)
    const int tid = threadIdx.x;
    const int tok = tid >> 6, lane = tid & 63;
    qs[tok][lane] = qk[(size_t)(t0 + tok) * 64 + lane];
    __syncthreads();
    const int h = (t0 >> 11) & 7;
    const int v = lane >> 2, r3 = lane & 3;
    const float* hp = hv + ((size_t)(h * 64) * 16 + v) * 4 + r3;
    float d = 0.f;
#pragma unroll
    for (int k = 0; k < 64; ++k) d += qs[tok][k] * hp[(size_t)k * 64];
    rot[tok][lane] = d;
    __syncthreads();
    if (tid < 16) {
        int tk = tid >> 2, r = tid & 3;
        float best = -rot[tk][0 * 4 + r];
        int bj = 0;
        for (int j = 1; j < 32; ++j) {
            float val = (j < 16) ? -rot[tk][j * 4 + r] : rot[tk][(j - 16) * 4 + r];
            if (val > best) { best = val; bj = j; }
        }
        loc2[(size_t)(t0 + tk) * 4 + r] = bj;
    }
}

// ---------------------------------------------------------------------------
// Stable counting sort per (b,h,r): 2048 keys, 32 buckets.
// st[(bh*4+r)*2048 + sorted_pos] = original position.
// ---------------------------------------------------------------------------
__global__ __launch_bounds__(256) void sort_kernel(const int* __restrict__ loc2,
                                                   int* __restrict__ st) {
    __shared__ int hist[32];
    __shared__ int base[32];
    const int gid = blockIdx.x;       // = bh*4 + r
    const int r = gid & 3, bh = gid >> 2;
    const int* lp = loc2 + (size_t)(bh * 2048) * 4 + r;
    const int tid = threadIdx.x;
    if (tid < 32) hist[tid] = 0;
    __syncthreads();
    for (int p = tid; p < 2048; p += 256) atomicAdd(&hist[lp[(size_t)p * 4]], 1);
    __syncthreads();
    if (tid == 0) {
        int acc = 0;
        for (int bkt = 0; bkt < 32; ++bkt) { base[bkt] = acc; acc += hist[bkt]; }
    }
    __syncthreads();
    if (tid < 32) {
        int o = base[tid];
        int* out = st + (size_t)gid * 2048;
        for (int p = 0; p < 2048; ++p)
            if (lp[(size_t)p * 4] == tid) out[o++] = p;
    }
}

// ---------------------------------------------------------------------------
// Chunked attention. One block per (b,h,r,chunk n): 64 queries x 192-key
// window x 64 feat.  Scatters vo and lse back to original token order.
// ---------------------------------------------------------------------------
constexpr int ATTN_K_F = WS_ * 65;        // raw K window (later reused for V)
constexpr int ATTN_P_F = CS_ * 193;       // probability matrix
constexpr int ATTN_S_F = WS_;             // key scales
constexpr int ATTN_I_N = WS_ + WS_ + WS_ * 4;  // Tk, Bk, Lk
constexpr size_t ATTN_LDS_BYTES = (size_t)(ATTN_K_F + ATTN_P_F + ATTN_S_F + ATTN_I_N) * 4;

__global__ __launch_bounds__(256) void attn_kernel(const float* __restrict__ qk,
                                                   const float* __restrict__ vv,
                                                   const int* __restrict__ loc2,
                                                   const int* __restrict__ st,
                                                   float* __restrict__ lseg,
                                                   float* __restrict__ vog) {
    extern __shared__ float smem[];
    float (*K)[65] = (float(*)[65])smem;                       // [192][65]
    float (*P)[193] = (float(*)[193])(smem + ATTN_K_F);        // [64][193]
    float* scaleK = smem + ATTN_K_F + ATTN_P_F;                // [192]
    int* Tk = (int*)(scaleK + ATTN_S_F);                       // [192]
    int* Bk = Tk + WS_;                                        // [192]
    int (*Lk)[4] = (int(*)[4])(Bk + WS_);                      // [192][4]

    const int gid = blockIdx.x;
    const int n = gid & 31;
    const int r = (gid >> 5) & 3;
    const int bh = gid >> 7;                 // b*8 + h
    const int tid = threadIdx.x;
    const int sbase = (bh * 4 + r) * 2048;

    // stage window token metadata
    for (int w = tid; w < WS_; w += 256) {
        int chunk = (n + 31 + (w >> 6)) & 31;        // n-1, n, n+1
        int t = st[(size_t)sbase + chunk * 64 + (w & 63)];
        Tk[w] = t;
        int4 l4 = *(const int4*)(loc2 + (size_t)(bh * 2048 + t) * 4);
        Lk[w][0] = l4.x; Lk[w][1] = l4.y; Lk[w][2] = l4.z; Lk[w][3] = l4.w;
        Bk[w] = (r == 0) ? l4.x : (r == 1) ? l4.y : (r == 2) ? l4.z : l4.w;
    }
    __syncthreads();
    // stage raw qk rows for the window
    for (int idx = tid; idx < WS_ * 64; idx += 256) {
        int w = idx >> 6, k = idx & 63;
        K[w][k] = qk[(size_t)(bh * 2048 + Tk[w]) * 64 + k];
    }
    __syncthreads();
    // per-key L2 norm -> scale
    for (int w = tid; w < WS_; w += 256) {
        float s = 0.f;
#pragma unroll
        for (int k = 0; k < 64; ++k) { float x = K[w][k]; s += x * x; }
        scaleK[w] = 1.0f / fmaxf(sqrtf(s), 1e-12f);
    }
    __syncthreads();

    const int ty = tid >> 4, tx = tid & 15;   // 16x16: rows ty*4+i, cols tx*12+j
    float acc[4][12];
#pragma unroll
    for (int i = 0; i < 4; ++i)
#pragma unroll
        for (int j = 0; j < 12; ++j) acc[i][j] = 0.f;

    for (int k = 0; k < 64; ++k) {
        float q[4], kv[12];
#pragma unroll
        for (int i = 0; i < 4; ++i) q[i] = K[64 + ty * 4 + i][k];
#pragma unroll
        for (int j = 0; j < 12; ++j) kv[j] = K[tx * 12 + j][k];
#pragma unroll
        for (int i = 0; i < 4; ++i)
#pragma unroll
            for (int j = 0; j < 12; ++j) acc[i][j] += q[i] * kv[j];
    }

    float logd[5];
#pragma unroll
    for (int dd = 0; dd < 5; ++dd) logd[dd] = logf((float)dd + 1e-9f);

    int Bq[4], Lq0[4], Lq1[4], Lq2[4], Lq3[4];
#pragma unroll
    for (int i = 0; i < 4; ++i) {
        int row = ty * 4 + i;
        Bq[i] = Bk[64 + row];
        Lq0[i] = Lk[64 + row][0]; Lq1[i] = Lk[64 + row][1];
        Lq2[i] = Lk[64 + row][2]; Lq3[i] = Lk[64 + row][3];
    }
#pragma unroll
    for (int i = 0; i < 4; ++i) {
        int row = ty * 4 + i;
#pragma unroll
        for (int j = 0; j < 12; ++j) {
            int col = tx * 12 + j;
            float val = acc[i][j] * (scaleK[col] * 0.125f);
            if (col == 64 + row) val = -100000.0f;            // self penalty
            if (Bk[col] != Bq[i]) val = NEGF;                 // different bucket
            int dup = (Lq0[i] == Lk[col][0]) + (Lq1[i] == Lk[col][1]) +
                      (Lq2[i] == Lk[col][2]) + (Lq3[i] == Lk[col][3]);
            acc[i][j] = val - logd[dup];
        }
    }

    // row softmax: reduce across the 16 tx lanes (same wave, lanes base+0..15)
#pragma unroll
    for (int i = 0; i < 4; ++i) {
        float mm = acc[i][0];
#pragma unroll
        for (int j = 1; j < 12; ++j) mm = fmaxf(mm, acc[i][j]);
        for (int off = 8; off; off >>= 1) mm = fmaxf(mm, __shfl_xor(mm, off));
        float ss = 0.f;
#pragma unroll
        for (int j = 0; j < 12; ++j) ss += expf(acc[i][j] - mm);
        for (int off = 8; off; off >>= 1) ss += __shfl_xor(ss, off);
        float lse = mm + logf(ss);
        int row = ty * 4 + i;
        if (tx == 0) lseg[(size_t)sbase + Tk[64 + row]] = lse;
#pragma unroll
        for (int j = 0; j < 12; ++j) P[row][tx * 12 + j] = expf(acc[i][j] - lse);
    }
    __syncthreads();
    // load V into the K region (reuse)
    for (int idx = tid; idx < WS_ * 64; idx += 256) {
        int w = idx >> 6, k = idx & 63;
        K[w][k] = vv[(size_t)(bh * 2048 + Tk[w]) * 64 + k];
    }
    __syncthreads();
    // PV: rows ty*4+i, out-cols tx*4+j
    float o[4][4] = {};
    for (int kk = 0; kk < WS_; ++kk) {
        float pv[4], vvv[4];
#pragma unroll
        for (int i = 0; i < 4; ++i) pv[i] = P[ty * 4 + i][kk];
#pragma unroll
        for (int j = 0; j < 4; ++j) vvv[j] = K[kk][tx * 4 + j];
#pragma unroll
        for (int i = 0; i < 4; ++i)
#pragma unroll
            for (int j = 0; j < 4; ++j) o[i][j] += pv[i] * vvv[j];
    }
#pragma unroll
    for (int i = 0; i < 4; ++i) {
        int row = ty * 4 + i;
        int t = Tk[64 + row];
        float4 val = make_float4(o[i][0], o[i][1], o[i][2], o[i][3]);
        *(float4*)(vog + ((size_t)sbase + t) * 64 + tx * 4) = val;
    }
}

// ---------------------------------------------------------------------------
// Combine rounds: out(b,h,s,k) = sum_r vo_r * softmax_r(lse).  Writes to
// att[(b*2048+s)*512 + h*64 + k] for the final projection.
// ---------------------------------------------------------------------------
__global__ __launch_bounds__(256) void combine_kernel(const float* __restrict__ vog,
                                                      const float* __restrict__ lseg,
                                                      float* __restrict__ att) {
    const int gid = blockIdx.x * 256 + threadIdx.x;  // 2*8*2048*64 total
    const int k = gid & 63;
    const int t = (gid >> 6) & 2047;
    const int bh = gid >> 17;
    const int b = bh >> 3, h = bh & 7;
    float l[4], vo[4];
#pragma unroll
    for (int r = 0; r < 4; ++r) {
        l[r] = lseg[(size_t)(bh * 4 + r) * 2048 + t];
        vo[r] = vog[((size_t)(bh * 4 + r) * 2048 + t) * 64 + k];
    }
    float m = fmaxf(fmaxf(l[0], l[1]), fmaxf(l[2], l[3]));
    float ss = expf(l[0] - m) + expf(l[1] - m) + expf(l[2] - m) + expf(l[3] - m);
    float lt = m + logf(ss);
    float out = 0.f;
#pragma unroll
    for (int r = 0; r < 4; ++r) out += expf(l[r] - lt) * vo[r];
    att[((size_t)(b * 2048 + t)) * 512 + h * 64 + k] = out;
}

// ---------------------------------------------------------------------------
extern "C" void kernel_launch(void* const* d_in, const int* in_sizes, int n_in,
                              void* d_out, int out_size, void* d_ws, size_t ws_size,
                              hipStream_t stream) {
    const float* x  = (const float*)d_in[0];
    const float* Wq = (const float*)d_in[1];
    const float* bq = (const float*)d_in[2];
    const float* Wv = (const float*)d_in[3];
    const float* bv = (const float*)d_in[4];
    const float* Wo = (const float*)d_in[5];
    const float* bo = (const float*)d_in[6];
    const float* hv = (const float*)d_in[7];

    float* qkbuf = (float*)d_ws;                        // 2*8*2048*64 f32
    float* vbuf  = qkbuf + 2097152;                     // 2*8*2048*64 f32
    int*   loc2  = (int*)(vbuf + 2097152);              // (b,h,s,4)   int
    int*   stbuf = loc2 + 131072;                       // (b,h,r,s)   int
    float* lseg  = (float*)(stbuf + 131072);            // (b,h,r,s)   f32
    float* vog   = lseg + 131072;                       // (b,h,r,s,k) f32
    float* att   = vog + 8388608;                       // (b,s,512)   f32

    dim3 gg(64, 8), blk(256);
    gemm_bias<<<gg, blk, 0, stream>>>(x, Wq, bq, qkbuf, 0);
    gemm_bias<<<gg, blk, 0, stream>>>(x, Wv, bv, vbuf, 0);
    hash_kernel<<<8192, 256, 0, stream>>>(qkbuf, hv, loc2);
    sort_kernel<<<64, 256, 0, stream>>>(loc2, stbuf);
    attn_kernel<<<2048, 256, ATTN_LDS_BYTES, stream>>>(qkbuf, vbuf, loc2, stbuf, lseg, vog);
    combine_kernel<<<8192, 256, 0, stream>>>(vog, lseg, att);
    gemm_bias<<<gg, blk, 0, stream>>>(att, Wo, bo, (float*)d_out, 1);
}

// Round 2
// 435.296 us; speedup vs baseline: 1.5949x; 1.5949x over previous
//
#include <hip/hip_runtime.h>
#include <hip/hip_bf16.h>
#include <math.h>

// Problem constants (b=2, s=2048, d=512, h=8, k=64, rounds=4, buckets=32, cs=64)
#define WS_ 192          // 3 * 64 (acn=1 window)
#define NEGF (-3.402823466e+38f)

// ---------------------------------------------------------------------------
// f32 GEMM: C = A(4096 x 512) @ W(512 x 512) + bias.
// mode 0: write to (b,h,s,k) layout ; mode 1: row-major direct.
// K-step 32, rows padded to 68 floats (16B-aligned, bank-quad stride 17).
// ---------------------------------------------------------------------------
__global__ __launch_bounds__(256) void gemm_bias(const float* __restrict__ A,
                                                 const float* __restrict__ W,
                                                 const float* __restrict__ bias,
                                                 float* __restrict__ C, int mode) {
    __shared__ float As[32][68];   // k-major: As[kk][i]
    __shared__ float Ws[32][68];   // k-major: Ws[kk][j]
    const int m0 = blockIdx.x * 64;
    const int n0 = blockIdx.y * 64;
    const int tid = threadIdx.x;
    const int ty = tid >> 4, tx = tid & 15;
    const int ci = tid & 7, ri = tid >> 3;    // A staging
    const int wk = tid >> 4, wt = tid & 15;   // W staging
    float acc[4][4] = {};
    for (int k0 = 0; k0 < 512; k0 += 32) {
        // stage A (transpose to k-major): 64 rows x 32 k
#pragma unroll
        for (int h = 0; h < 2; ++h) {
            int i = ri + h * 32;
            float4 a4 = *(const float4*)(A + (size_t)(m0 + i) * 512 + k0 + ci * 4);
            As[ci * 4 + 0][i] = a4.x;
            As[ci * 4 + 1][i] = a4.y;
            As[ci * 4 + 2][i] = a4.z;
            As[ci * 4 + 3][i] = a4.w;
        }
        // stage W: rows contiguous in n
#pragma unroll
        for (int h = 0; h < 2; ++h) {
            int kk = wk + h * 16;
            float4 w4 = *(const float4*)(W + (size_t)(k0 + kk) * 512 + n0 + wt * 4);
            *(float4*)(&Ws[kk][wt * 4]) = w4;
        }
        __syncthreads();
#pragma unroll
        for (int kk = 0; kk < 32; ++kk) {
            float4 a4 = *(float4*)(&As[kk][ty * 4]);
            float4 w4 = *(float4*)(&Ws[kk][tx * 4]);
            float a[4] = {a4.x, a4.y, a4.z, a4.w};
            float w[4] = {w4.x, w4.y, w4.z, w4.w};
#pragma unroll
            for (int i = 0; i < 4; ++i)
#pragma unroll
                for (int j = 0; j < 4; ++j) acc[i][j] += a[i] * w[j];
        }
        __syncthreads();
    }
#pragma unroll
    for (int i = 0; i < 4; ++i) {
        int m = m0 + ty * 4 + i;
        float4 val = make_float4(acc[i][0] + bias[n0 + tx * 4 + 0],
                                 acc[i][1] + bias[n0 + tx * 4 + 1],
                                 acc[i][2] + bias[n0 + tx * 4 + 2],
                                 acc[i][3] + bias[n0 + tx * 4 + 3]);
        if (mode == 0) {
            int b = m >> 11, s = m & 2047;
            int h = n0 >> 6;
            *(float4*)(C + ((size_t)(((b << 3) + h) * 2048 + s)) * 64 + tx * 4) = val;
        } else {
            *(float4*)(C + (size_t)m * 512 + n0 + tx * 4) = val;
        }
    }
}

// ---------------------------------------------------------------------------
// LSH hashing: bucket[r] = argmax over 32 of concat(-rot, rot).
// loc2[token*4 + r] = bucket id (0..31).
// ---------------------------------------------------------------------------
__global__ __launch_bounds__(256) void hash_kernel(const float* __restrict__ qk,
                                                   const float* __restrict__ hv,
                                                   int* __restrict__ loc2) {
    __shared__ float qs[4][64];
    __shared__ float rot[4][64];  // [tok][v*4+r]
    const int t0 = blockIdx.x * 4;
    const int tid = threadIdx.x;
    const int tok = tid >> 6, lane = tid & 63;
    qs[tok][lane] = qk[(size_t)(t0 + tok) * 64 + lane];
    __syncthreads();
    const int h = (t0 >> 11) & 7;
    const int v = lane >> 2, r3 = lane & 3;
    const float* hp = hv + ((size_t)(h * 64) * 16 + v) * 4 + r3;
    float d = 0.f;
#pragma unroll
    for (int k = 0; k < 64; ++k) d += qs[tok][k] * hp[(size_t)k * 64];
    rot[tok][lane] = d;
    __syncthreads();
    if (tid < 16) {
        int tk = tid >> 2, r = tid & 3;
        float best = -rot[tk][0 * 4 + r];
        int bj = 0;
        for (int j = 1; j < 32; ++j) {
            float val = (j < 16) ? -rot[tk][j * 4 + r] : rot[tk][(j - 16) * 4 + r];
            if (val > best) { best = val; bj = j; }
        }
        loc2[(size_t)(t0 + tk) * 4 + r] = bj;
    }
}

// ---------------------------------------------------------------------------
// Stable counting sort per (b,h,r): 2048 keys, 32 buckets.
// ---------------------------------------------------------------------------
__global__ __launch_bounds__(256) void sort_kernel(const int* __restrict__ loc2,
                                                   int* __restrict__ st) {
    __shared__ int hist[32];
    __shared__ int base[32];
    const int gid = blockIdx.x;       // = bh*4 + r
    const int r = gid & 3, bh = gid >> 2;
    const int* lp = loc2 + (size_t)(bh * 2048) * 4 + r;
    const int tid = threadIdx.x;
    if (tid < 32) hist[tid] = 0;
    __syncthreads();
    for (int p = tid; p < 2048; p += 256) atomicAdd(&hist[lp[(size_t)p * 4]], 1);
    __syncthreads();
    if (tid == 0) {
        int acc = 0;
        for (int bkt = 0; bkt < 32; ++bkt) { base[bkt] = acc; acc += hist[bkt]; }
    }
    __syncthreads();
    if (tid < 32) {
        int o = base[tid];
        int* out = st + (size_t)gid * 2048;
        for (int p = 0; p < 2048; ++p)
            if (lp[(size_t)p * 4] == tid) out[o++] = p;
    }
}

// ---------------------------------------------------------------------------
// Chunked attention, v2. One block per (b,h,r,chunk). 51.5 KB LDS ->
// 3 blocks/CU.  K/V staged XOR-swizzled (float4 quad ^= row&15), all inner
// LDS traffic is b128.  P kept in registers; PV via 16-lane shfl broadcast.
// ---------------------------------------------------------------------------
__global__ __launch_bounds__(256, 3) void attn_kernel(const float* __restrict__ qk,
                                                      const float* __restrict__ vv,
                                                      const int* __restrict__ loc2,
                                                      const int* __restrict__ st,
                                                      float* __restrict__ lseg,
                                                      float* __restrict__ vog) {
    __shared__ float Kst[WS_ * 64];   // swizzled rows of K (later V)
    __shared__ float scaleK[WS_];
    __shared__ int Tk[WS_];
    __shared__ int Lp[WS_];           // packed 4x8-bit per-round bucket ids

    const int gid = blockIdx.x;
    const int n = gid & 31;
    const int r = (gid >> 5) & 3;
    const int bh = gid >> 7;
    const int tid = threadIdx.x;
    const int sbase = (bh * 4 + r) * 2048;

    if (tid < WS_) {
        int w = tid;
        int chunk = (n + 31 + (w >> 6)) & 31;
        int t = st[(size_t)sbase + chunk * 64 + (w & 63)];
        Tk[w] = t;
        int4 l4 = *(const int4*)(loc2 + (size_t)(bh * 2048 + t) * 4);
        Lp[w] = l4.x | (l4.y << 8) | (l4.z << 16) | (l4.w << 24);
    }
    __syncthreads();

    const int fs = tid & 15, wsb = tid >> 4;
    // stage K (swizzled)
#pragma unroll
    for (int w0 = 0; w0 < WS_; w0 += 16) {
        int w = w0 + wsb;
        float4 v4 = *(const float4*)(qk + ((size_t)(bh * 2048 + Tk[w])) * 64 + fs * 4);
        *(float4*)(Kst + w * 64 + ((fs ^ (w & 15)) << 2)) = v4;
    }
    __syncthreads();
    // per-key scale = (k^-0.5) / ||k||
    for (int w = tid; w < WS_; w += 256) {
        float s = 0.f;
#pragma unroll
        for (int f = 0; f < 16; ++f) {
            float4 v4 = *(float4*)(Kst + w * 64 + ((f ^ (w & 15)) << 2));
            s += v4.x * v4.x + v4.y * v4.y + v4.z * v4.z + v4.w * v4.w;
        }
        scaleK[w] = 0.125f / fmaxf(sqrtf(s), 1e-12f);
    }
    __syncthreads();

    const int tx = tid & 15, ty = tid >> 4;   // rows ty*4+i, cols j*16+tx
    float p[4][12];
#pragma unroll
    for (int i = 0; i < 4; ++i)
#pragma unroll
        for (int j = 0; j < 12; ++j) p[i][j] = 0.f;

    for (int k4 = 0; k4 < 16; ++k4) {
        float4 q[4];
#pragma unroll
        for (int i = 0; i < 4; ++i) {
            int row = 64 + ty * 4 + i;
            q[i] = *(float4*)(Kst + row * 64 + ((k4 ^ (row & 15)) << 2));
        }
#pragma unroll
        for (int j = 0; j < 12; ++j) {
            int c = j * 16 + tx;
            float4 kv = *(float4*)(Kst + c * 64 + ((k4 ^ tx) << 2));
#pragma unroll
            for (int i = 0; i < 4; ++i)
                p[i][j] += q[i].x * kv.x + q[i].y * kv.y + q[i].z * kv.z + q[i].w * kv.w;
        }
    }

    // masks + softmax (rows owned per thread, cols across tx lanes)
    int lpq[4];
#pragma unroll
    for (int i = 0; i < 4; ++i) lpq[i] = Lp[64 + ty * 4 + i];
    const int rsh = r * 8;
#pragma unroll
    for (int i = 0; i < 4; ++i) {
        int row = ty * 4 + i;
        int lq = lpq[i];
        int bq = (lq >> rsh) & 255;
#pragma unroll
        for (int j = 0; j < 12; ++j) {
            int c = j * 16 + tx;
            float val = p[i][j] * scaleK[c];
            int lk = Lp[c];
            if (c == 64 + row) val = -100000.0f;
            if (((lk >> rsh) & 255) != bq) val = NEGF;
            int x = lq ^ lk;
            int dup = ((x & 255) == 0) + (((x >> 8) & 255) == 0) +
                      (((x >> 16) & 255) == 0) + (((x >> 24) & 255) == 0);
            float ld = dup < 2 ? (dup ? 0.0f : -20.72326584f)
                               : (dup == 2 ? 0.69314718f
                                           : (dup == 3 ? 1.09861229f : 1.38629436f));
            p[i][j] = val - ld;
        }
    }

#pragma unroll
    for (int i = 0; i < 4; ++i) {
        float mm = p[i][0];
#pragma unroll
        for (int j = 1; j < 12; ++j) mm = fmaxf(mm, p[i][j]);
        for (int off = 8; off; off >>= 1) mm = fmaxf(mm, __shfl_xor(mm, off, 16));
        float ss = 0.f;
#pragma unroll
        for (int j = 0; j < 12; ++j) {
            float e = __expf(p[i][j] - mm);
            p[i][j] = e;
            ss += e;
        }
        for (int off = 8; off; off >>= 1) ss += __shfl_xor(ss, off, 16);
        float lse = mm + __logf(ss);
        if (tx == 0) lseg[(size_t)sbase + Tk[64 + ty * 4 + i]] = lse;
        float inv = 1.0f / ss;
#pragma unroll
        for (int j = 0; j < 12; ++j) p[i][j] *= inv;
    }

    __syncthreads();
    // stage V over K (swizzled)
#pragma unroll
    for (int w0 = 0; w0 < WS_; w0 += 16) {
        int w = w0 + wsb;
        float4 v4 = *(const float4*)(vv + ((size_t)(bh * 2048 + Tk[w])) * 64 + fs * 4);
        *(float4*)(Kst + w * 64 + ((fs ^ (w & 15)) << 2)) = v4;
    }
    __syncthreads();

    float4 o[4];
#pragma unroll
    for (int i = 0; i < 4; ++i) o[i] = make_float4(0.f, 0.f, 0.f, 0.f);
#pragma unroll
    for (int j = 0; j < 12; ++j) {
        for (int t = 0; t < 16; ++t) {
            int c = j * 16 + t;
            float4 v4 = *(float4*)(Kst + c * 64 + ((tx ^ t) << 2));
            float pb0 = __shfl(p[0][j], t, 16);
            float pb1 = __shfl(p[1][j], t, 16);
            float pb2 = __shfl(p[2][j], t, 16);
            float pb3 = __shfl(p[3][j], t, 16);
            o[0].x += pb0 * v4.x; o[0].y += pb0 * v4.y; o[0].z += pb0 * v4.z; o[0].w += pb0 * v4.w;
            o[1].x += pb1 * v4.x; o[1].y += pb1 * v4.y; o[1].z += pb1 * v4.z; o[1].w += pb1 * v4.w;
            o[2].x += pb2 * v4.x; o[2].y += pb2 * v4.y; o[2].z += pb2 * v4.z; o[2].w += pb2 * v4.w;
            o[3].x += pb3 * v4.x; o[3].y += pb3 * v4.y; o[3].z += pb3 * v4.z; o[3].w += pb3 * v4.w;
        }
    }
#pragma unroll
    for (int i = 0; i < 4; ++i) {
        int row = 64 + ty * 4 + i;
        *(float4*)(vog + ((size_t)sbase + Tk[row]) * 64 + tx * 4) = o[i];
    }
}

// ---------------------------------------------------------------------------
// Combine rounds: out = sum_r vo_r * softmax_r(lse), to (b,s,512) layout.
// ---------------------------------------------------------------------------
__global__ __launch_bounds__(256) void combine_kernel(const float* __restrict__ vog,
                                                      const float* __restrict__ lseg,
                                                      float* __restrict__ att) {
    const int gid = blockIdx.x * 256 + threadIdx.x;
    const int k = gid & 63;
    const int t = (gid >> 6) & 2047;
    const int bh = gid >> 17;
    const int b = bh >> 3, h = bh & 7;
    float l[4], vo[4];
#pragma unroll
    for (int r = 0; r < 4; ++r) {
        l[r] = lseg[(size_t)(bh * 4 + r) * 2048 + t];
        vo[r] = vog[((size_t)(bh * 4 + r) * 2048 + t) * 64 + k];
    }
    float m = fmaxf(fmaxf(l[0], l[1]), fmaxf(l[2], l[3]));
    float ss = expf(l[0] - m) + expf(l[1] - m) + expf(l[2] - m) + expf(l[3] - m);
    float lt = m + logf(ss);
    float out = 0.f;
#pragma unroll
    for (int r = 0; r < 4; ++r) out += expf(l[r] - lt) * vo[r];
    att[((size_t)(b * 2048 + t)) * 512 + h * 64 + k] = out;
}

// ---------------------------------------------------------------------------
extern "C" void kernel_launch(void* const* d_in, const int* in_sizes, int n_in,
                              void* d_out, int out_size, void* d_ws, size_t ws_size,
                              hipStream_t stream) {
    const float* x  = (const float*)d_in[0];
    const float* Wq = (const float*)d_in[1];
    const float* bq = (const float*)d_in[2];
    const float* Wv = (const float*)d_in[3];
    const float* bv = (const float*)d_in[4];
    const float* Wo = (const float*)d_in[5];
    const float* bo = (const float*)d_in[6];
    const float* hv = (const float*)d_in[7];

    float* qkbuf = (float*)d_ws;                        // 2*8*2048*64 f32
    float* vbuf  = qkbuf + 2097152;
    int*   loc2  = (int*)(vbuf + 2097152);              // (b,h,s,4)
    int*   stbuf = loc2 + 131072;                       // (b,h,r,s)
    float* lseg  = (float*)(stbuf + 131072);            // (b,h,r,s)
    float* vog   = lseg + 131072;                       // (b,h,r,s,k)
    float* att   = vog + 8388608;                       // (b,s,512)

    dim3 gg(64, 8), blk(256);
    gemm_bias<<<gg, blk, 0, stream>>>(x, Wq, bq, qkbuf, 0);
    gemm_bias<<<gg, blk, 0, stream>>>(x, Wv, bv, vbuf, 0);
    hash_kernel<<<8192, 256, 0, stream>>>(qkbuf, hv, loc2);
    sort_kernel<<<64, 256, 0, stream>>>(loc2, stbuf);
    attn_kernel<<<2048, 256, 0, stream>>>(qkbuf, vbuf, loc2, stbuf, lseg, vog);
    combine_kernel<<<8192, 256, 0, stream>>>(vog, lseg, att);
    gemm_bias<<<gg, blk, 0, stream>>>(att, Wo, bo, (float*)d_out, 1);
}

// Round 3
// 333.179 us; speedup vs baseline: 2.0838x; 1.3065x over previous
//
#include <hip/hip_runtime.h>
#include <hip/hip_bf16.h>
#include <math.h>

// Problem constants (b=2, s=2048, d=512, h=8, k=64, rounds=4, buckets=32, cs=64)
#define WS_ 192          // 3 * 64 (acn=1 window)
#define NEGF (-3.402823466e+38f)

typedef __attribute__((ext_vector_type(8))) short short8;
typedef __attribute__((ext_vector_type(4))) float f32x4;

static __device__ __forceinline__ unsigned int f2bf(float f) {
    unsigned int u = __float_as_uint(f);
    return (u + 0x7FFFu + ((u >> 16) & 1u)) >> 16;
}
// pack f32 into (hi bf16 | lo bf16<<16), hi+lo ~ exact
static __device__ __forceinline__ unsigned int packsplit(float v) {
    unsigned int h = f2bf(v);
    float hf = __uint_as_float(h << 16);
    unsigned int l = f2bf(v - hf);
    return h | (l << 16);
}
static __device__ __forceinline__ void mkfrag(uint4 a, uint4 b, short8 &h, short8 &l) {
    h[0]=(short)(a.x&0xFFFFu); h[1]=(short)(a.y&0xFFFFu); h[2]=(short)(a.z&0xFFFFu); h[3]=(short)(a.w&0xFFFFu);
    h[4]=(short)(b.x&0xFFFFu); h[5]=(short)(b.y&0xFFFFu); h[6]=(short)(b.z&0xFFFFu); h[7]=(short)(b.w&0xFFFFu);
    l[0]=(short)(a.x>>16);     l[1]=(short)(a.y>>16);     l[2]=(short)(a.z>>16);     l[3]=(short)(a.w>>16);
    l[4]=(short)(b.x>>16);     l[5]=(short)(b.y>>16);     l[6]=(short)(b.z>>16);     l[7]=(short)(b.w>>16);
}

// ---------------------------------------------------------------------------
// f32 GEMM: C = A(4096 x 512) @ W(512 x 512) + bias.  (unchanged this round)
// ---------------------------------------------------------------------------
__global__ __launch_bounds__(256) void gemm_bias(const float* __restrict__ A,
                                                 const float* __restrict__ W,
                                                 const float* __restrict__ bias,
                                                 float* __restrict__ C, int mode) {
    __shared__ float As[32][68];
    __shared__ float Ws[32][68];
    const int m0 = blockIdx.x * 64;
    const int n0 = blockIdx.y * 64;
    const int tid = threadIdx.x;
    const int ty = tid >> 4, tx = tid & 15;
    const int ci = tid & 7, ri = tid >> 3;
    const int wk = tid >> 4, wt = tid & 15;
    float acc[4][4] = {};
    for (int k0 = 0; k0 < 512; k0 += 32) {
#pragma unroll
        for (int h = 0; h < 2; ++h) {
            int i = ri + h * 32;
            float4 a4 = *(const float4*)(A + (size_t)(m0 + i) * 512 + k0 + ci * 4);
            As[ci * 4 + 0][i] = a4.x;
            As[ci * 4 + 1][i] = a4.y;
            As[ci * 4 + 2][i] = a4.z;
            As[ci * 4 + 3][i] = a4.w;
        }
#pragma unroll
        for (int h = 0; h < 2; ++h) {
            int kk = wk + h * 16;
            float4 w4 = *(const float4*)(W + (size_t)(k0 + kk) * 512 + n0 + wt * 4);
            *(float4*)(&Ws[kk][wt * 4]) = w4;
        }
        __syncthreads();
#pragma unroll
        for (int kk = 0; kk < 32; ++kk) {
            float4 a4 = *(float4*)(&As[kk][ty * 4]);
            float4 w4 = *(float4*)(&Ws[kk][tx * 4]);
            float a[4] = {a4.x, a4.y, a4.z, a4.w};
            float w[4] = {w4.x, w4.y, w4.z, w4.w};
#pragma unroll
            for (int i = 0; i < 4; ++i)
#pragma unroll
                for (int j = 0; j < 4; ++j) acc[i][j] += a[i] * w[j];
        }
        __syncthreads();
    }
#pragma unroll
    for (int i = 0; i < 4; ++i) {
        int m = m0 + ty * 4 + i;
        float4 val = make_float4(acc[i][0] + bias[n0 + tx * 4 + 0],
                                 acc[i][1] + bias[n0 + tx * 4 + 1],
                                 acc[i][2] + bias[n0 + tx * 4 + 2],
                                 acc[i][3] + bias[n0 + tx * 4 + 3]);
        if (mode == 0) {
            int b = m >> 11, s = m & 2047;
            int h = n0 >> 6;
            *(float4*)(C + ((size_t)(((b << 3) + h) * 2048 + s)) * 64 + tx * 4) = val;
        } else {
            *(float4*)(C + (size_t)m * 512 + n0 + tx * 4) = val;
        }
    }
}

// ---------------------------------------------------------------------------
// LSH hashing (unchanged): bucket[r] = argmax over 32 of concat(-rot, rot).
// ---------------------------------------------------------------------------
__global__ __launch_bounds__(256) void hash_kernel(const float* __restrict__ qk,
                                                   const float* __restrict__ hv,
                                                   int* __restrict__ loc2) {
    __shared__ float qs[4][64];
    __shared__ float rot[4][64];
    const int t0 = blockIdx.x * 4;
    const int tid = threadIdx.x;
    const int tok = tid >> 6, lane = tid & 63;
    qs[tok][lane] = qk[(size_t)(t0 + tok) * 64 + lane];
    __syncthreads();
    const int h = (t0 >> 11) & 7;
    const int v = lane >> 2, r3 = lane & 3;
    const float* hp = hv + ((size_t)(h * 64) * 16 + v) * 4 + r3;
    float d = 0.f;
#pragma unroll
    for (int k = 0; k < 64; ++k) d += qs[tok][k] * hp[(size_t)k * 64];
    rot[tok][lane] = d;
    __syncthreads();
    if (tid < 16) {
        int tk = tid >> 2, r = tid & 3;
        float best = -rot[tk][0 * 4 + r];
        int bj = 0;
        for (int j = 1; j < 32; ++j) {
            float val = (j < 16) ? -rot[tk][j * 4 + r] : rot[tk][(j - 16) * 4 + r];
            if (val > best) { best = val; bj = j; }
        }
        loc2[(size_t)(t0 + tk) * 4 + r] = bj;
    }
}

// ---------------------------------------------------------------------------
// Stable counting sort per (b,h,r), one wave per block, ballot-ranked.
// ---------------------------------------------------------------------------
__global__ __launch_bounds__(64) void sort_kernel(const int* __restrict__ loc2,
                                                  int* __restrict__ st) {
    __shared__ int base[32];
    __shared__ int cnt[32];
    const int gid = blockIdx.x;       // = bh*4 + r
    const int r = gid & 3, bh = gid >> 2;
    const int lane = threadIdx.x;
    if (lane < 32) { base[lane] = 0; cnt[lane] = 0; }
    __syncthreads();
    for (int chunk = 0; chunk < 32; ++chunk) {
        int b = loc2[(size_t)(bh * 2048 + chunk * 64 + lane) * 4 + r];
        atomicAdd(&base[b], 1);
    }
    __syncthreads();
    if (lane == 0) {
        int acc = 0;
        for (int k = 0; k < 32; ++k) { int h = base[k]; base[k] = acc; acc += h; }
    }
    __syncthreads();
    const unsigned long long lower_mask = (lane == 0) ? 0ull : ((~0ull) >> (64 - lane));
    for (int chunk = 0; chunk < 32; ++chunk) {
        int p = chunk * 64 + lane;
        int b = loc2[(size_t)(bh * 2048 + p) * 4 + r];
#pragma unroll 1
        for (int bkt = 0; bkt < 32; ++bkt) {
            unsigned long long m = __ballot(b == bkt);
            if (b == bkt) {
                int lower = __popcll(m & lower_mask);
                int rank = base[bkt] + cnt[bkt] + lower;
                st[(size_t)gid * 2048 + rank] = p;
                if (lower == 0) cnt[bkt] += (int)__popcll(m);   // leader updates
            }
        }
    }
}

// ---------------------------------------------------------------------------
// Chunked attention v3: split-bf16 MFMA (hi+lo, 3-term) for QK^T and PV.
// One block per (b,h,r,chunk); 4 waves; wave w owns queries [16w,16w+16).
// Kst: packed (hi|lo) u32, quad-XOR-swizzled; K rows then V^T rows (reused).
// Swapped QK^T (S^T = K Q^T) -> softmax is register-local per lane.
// ---------------------------------------------------------------------------
#define KQUAD(row, qd) (((row) << 6) + ((((qd) ^ ((row) & 15))) << 2))

__global__ __launch_bounds__(256, 3) void attn_kernel(const float* __restrict__ qk,
                                                      const float* __restrict__ vv,
                                                      const int* __restrict__ loc2,
                                                      const int* __restrict__ st,
                                                      float* __restrict__ lseg,
                                                      float* __restrict__ vog) {
    __shared__ __align__(16) unsigned int Kst[WS_ * 64];   // 48 KB, K then V^T
    __shared__ float scaleK[WS_];
    __shared__ int Tk[WS_];
    __shared__ int Lp[WS_];

    const int gid = blockIdx.x;
    const int n = gid & 31;
    const int r = (gid >> 5) & 3;
    const int bh = gid >> 7;
    const int tid = threadIdx.x;
    const int sbase = (bh * 4 + r) * 2048;
    const int lane = tid & 63;
    const int wv = tid >> 6;
    const int lx = lane & 15;
    const int hi = lane >> 4;

    if (tid < WS_) {
        int w = tid;
        int chunk = (n + 31 + (w >> 6)) & 31;
        int t = st[(size_t)sbase + chunk * 64 + (w & 63)];
        Tk[w] = t;
        int4 l4 = *(const int4*)(loc2 + (size_t)(bh * 2048 + t) * 4);
        Lp[w] = l4.x | (l4.y << 8) | (l4.z << 16) | (l4.w << 24);
    }
    __syncthreads();

    const int fs = tid & 15, wsb = tid >> 4;
    // ---- stage K (split-packed, swizzled) + per-row norm -> scaleK
#pragma unroll
    for (int it = 0; it < 12; ++it) {
        int row = it * 16 + wsb;
        const float4 v4 = *(const float4*)(qk + ((size_t)(bh * 2048 + Tk[row])) * 64 + fs * 4);
        float ss = v4.x * v4.x + v4.y * v4.y + v4.z * v4.z + v4.w * v4.w;
        ss += __shfl_xor(ss, 1, 16); ss += __shfl_xor(ss, 2, 16);
        ss += __shfl_xor(ss, 4, 16); ss += __shfl_xor(ss, 8, 16);
        if (fs == 0) scaleK[row] = 0.125f / fmaxf(sqrtf(ss), 1e-12f);
        uint4 pk;
        pk.x = packsplit(v4.x); pk.y = packsplit(v4.y);
        pk.z = packsplit(v4.z); pk.w = packsplit(v4.w);
        *(uint4*)(&Kst[KQUAD(row, fs)]) = pk;
    }
    __syncthreads();

    // ---- QK^T (swapped): S^T[c][q], A = K rows, B = Q^T
    short8 Bh[2], Bl[2];
    {
        int qrow = 64 + wv * 16 + lx;
#pragma unroll
        for (int ks = 0; ks < 2; ++ks) {
            int qd0 = ks * 8 + hi * 2;
            uint4 a = *(const uint4*)(&Kst[KQUAD(qrow, qd0)]);
            uint4 b = *(const uint4*)(&Kst[KQUAD(qrow, qd0 + 1)]);
            mkfrag(a, b, Bh[ks], Bl[ks]);
        }
    }
    f32x4 s[12];
#pragma unroll
    for (int ct = 0; ct < 12; ++ct) {
        f32x4 acc = {0.f, 0.f, 0.f, 0.f};
#pragma unroll
        for (int ks = 0; ks < 2; ++ks) {
            int arow = ct * 16 + lx;
            int qd0 = ks * 8 + hi * 2;
            uint4 a = *(const uint4*)(&Kst[KQUAD(arow, qd0)]);
            uint4 b = *(const uint4*)(&Kst[KQUAD(arow, qd0 + 1)]);
            short8 Ah, Al; mkfrag(a, b, Ah, Al);
            acc = __builtin_amdgcn_mfma_f32_16x16x32_bf16(Ah, Bh[ks], acc, 0, 0, 0);
            acc = __builtin_amdgcn_mfma_f32_16x16x32_bf16(Ah, Bl[ks], acc, 0, 0, 0);
            acc = __builtin_amdgcn_mfma_f32_16x16x32_bf16(Al, Bh[ks], acc, 0, 0, 0);
        }
        s[ct] = acc;
    }
    __syncthreads();   // all K reads done; Kst free for V^T

    // ---- stage V^T (split-packed, swizzled): Vt[f][c] at f*192 + swz(c)*4
#pragma unroll
    for (int it = 0; it < 12; ++it) {
        int c = it * 16 + wsb;
        const float4 v4 = *(const float4*)(vv + ((size_t)(bh * 2048 + Tk[c])) * 64 + fs * 4);
        float vals[4] = {v4.x, v4.y, v4.z, v4.w};
#pragma unroll
        for (int j = 0; j < 4; ++j) {
            int f = fs * 4 + j;
            int phys = (c >> 2) ^ (f & 15) ^ ((f >> 2) & 3);
            Kst[f * 192 + (phys << 2) + (c & 3)] = packsplit(vals[j]);
        }
    }

    // ---- masks + register softmax (lane owns q = strip+lx, 48 c-values)
    const int qw = 64 + wv * 16 + lx;
    const int lq = Lp[qw];
    const int rsh = r * 8;
    const int bq = (lq >> rsh) & 255;
    float mx = -3.0e38f;
#pragma unroll
    for (int ct = 0; ct < 12; ++ct) {
#pragma unroll
        for (int rr = 0; rr < 4; ++rr) {
            int c = ct * 16 + hi * 4 + rr;
            float val = s[ct][rr] * scaleK[c];
            int lk = Lp[c];
            if (c == qw) val = -100000.0f;
            if (((lk >> rsh) & 255) != bq) val = NEGF;
            int x = lq ^ lk;
            int dup = ((x & 255) == 0) + (((x >> 8) & 255) == 0) +
                      (((x >> 16) & 255) == 0) + (((x >> 24) & 255) == 0);
            float ld = dup < 2 ? (dup ? 0.0f : -20.72326584f)
                               : (dup == 2 ? 0.69314718f
                                           : (dup == 3 ? 1.09861229f : 1.38629436f));
            val -= ld;
            s[ct][rr] = val;
            mx = fmaxf(mx, val);
        }
    }
    mx = fmaxf(mx, __shfl_xor(mx, 16));
    mx = fmaxf(mx, __shfl_xor(mx, 32));
    float ssum = 0.f;
#pragma unroll
    for (int ct = 0; ct < 12; ++ct)
#pragma unroll
        for (int rr = 0; rr < 4; ++rr) {
            float e = __expf(s[ct][rr] - mx);
            s[ct][rr] = e;
            ssum += e;
        }
    ssum += __shfl_xor(ssum, 16);
    ssum += __shfl_xor(ssum, 32);
    float lse = mx + __logf(ssum);
    if (hi == 0) lseg[(size_t)sbase + Tk[qw]] = lse;
    float inv = 1.0f / ssum;
    unsigned int pu[12][4];
#pragma unroll
    for (int ct = 0; ct < 12; ++ct)
#pragma unroll
        for (int rr = 0; rr < 4; ++rr)
            pu[ct][rr] = packsplit(s[ct][rr] * inv);
    __syncthreads();   // V^T staged

    // ---- PV (swapped): O^T[f][q], A = V^T rows, B = P^T (shfl-gathered)
    f32x4 o[4] = {{0.f,0.f,0.f,0.f},{0.f,0.f,0.f,0.f},{0.f,0.f,0.f,0.f},{0.f,0.f,0.f,0.f}};
    const int hsel = hi & 2;
    const int hb = 2 * (hi & 1);
#pragma unroll
    for (int ks = 0; ks < 6; ++ks) {
        short8 Ph, Pl;
#pragma unroll
        for (int e = 0; e < 8; ++e) {
            int srcl = ((hb + (e >> 2)) << 4) | lx;
            unsigned int u0 = (unsigned int)__shfl((int)pu[2 * ks][e & 3], srcl, 64);
            unsigned int u1 = (unsigned int)__shfl((int)pu[2 * ks + 1][e & 3], srcl, 64);
            unsigned int ue = hsel ? u1 : u0;
            Ph[e] = (short)(ue & 0xFFFFu);
            Pl[e] = (short)(ue >> 16);
        }
#pragma unroll
        for (int ft = 0; ft < 4; ++ft) {
            int f = ft * 16 + lx;
            int qd0 = ks * 8 + hi * 2;
            int sw = (f & 15) ^ ((f >> 2) & 3);
            uint4 a = *(const uint4*)(&Kst[f * 192 + (((qd0) ^ sw) << 2)]);
            uint4 b = *(const uint4*)(&Kst[f * 192 + (((qd0 + 1) ^ sw) << 2)]);
            short8 Vh, Vl; mkfrag(a, b, Vh, Vl);
            o[ft] = __builtin_amdgcn_mfma_f32_16x16x32_bf16(Vh, Ph, o[ft], 0, 0, 0);
            o[ft] = __builtin_amdgcn_mfma_f32_16x16x32_bf16(Vh, Pl, o[ft], 0, 0, 0);
            o[ft] = __builtin_amdgcn_mfma_f32_16x16x32_bf16(Vl, Ph, o[ft], 0, 0, 0);
        }
    }
    const int tko = Tk[qw];
#pragma unroll
    for (int ft = 0; ft < 4; ++ft) {
        float4 w4 = make_float4(o[ft][0], o[ft][1], o[ft][2], o[ft][3]);
        *(float4*)(vog + ((size_t)sbase + tko) * 64 + ft * 16 + hi * 4) = w4;
    }
}

// ---------------------------------------------------------------------------
// Combine rounds (unchanged).
// ---------------------------------------------------------------------------
__global__ __launch_bounds__(256) void combine_kernel(const float* __restrict__ vog,
                                                      const float* __restrict__ lseg,
                                                      float* __restrict__ att) {
    const int gid = blockIdx.x * 256 + threadIdx.x;
    const int k = gid & 63;
    const int t = (gid >> 6) & 2047;
    const int bh = gid >> 17;
    const int b = bh >> 3, h = bh & 7;
    float l[4], vo[4];
#pragma unroll
    for (int r = 0; r < 4; ++r) {
        l[r] = lseg[(size_t)(bh * 4 + r) * 2048 + t];
        vo[r] = vog[((size_t)(bh * 4 + r) * 2048 + t) * 64 + k];
    }
    float m = fmaxf(fmaxf(l[0], l[1]), fmaxf(l[2], l[3]));
    float ss = expf(l[0] - m) + expf(l[1] - m) + expf(l[2] - m) + expf(l[3] - m);
    float lt = m + logf(ss);
    float out = 0.f;
#pragma unroll
    for (int r = 0; r < 4; ++r) out += expf(l[r] - lt) * vo[r];
    att[((size_t)(b * 2048 + t)) * 512 + h * 64 + k] = out;
}

// ---------------------------------------------------------------------------
extern "C" void kernel_launch(void* const* d_in, const int* in_sizes, int n_in,
                              void* d_out, int out_size, void* d_ws, size_t ws_size,
                              hipStream_t stream) {
    const float* x  = (const float*)d_in[0];
    const float* Wq = (const float*)d_in[1];
    const float* bq = (const float*)d_in[2];
    const float* Wv = (const float*)d_in[3];
    const float* bv = (const float*)d_in[4];
    const float* Wo = (const float*)d_in[5];
    const float* bo = (const float*)d_in[6];
    const float* hv = (const float*)d_in[7];

    float* qkbuf = (float*)d_ws;                        // 2*8*2048*64 f32
    float* vbuf  = qkbuf + 2097152;
    int*   loc2  = (int*)(vbuf + 2097152);              // (b,h,s,4)
    int*   stbuf = loc2 + 131072;                       // (b,h,r,s)
    float* lseg  = (float*)(stbuf + 131072);            // (b,h,r,s)
    float* vog   = lseg + 131072;                       // (b,h,r,s,k)
    float* att   = vog + 8388608;                       // (b,s,512)

    dim3 gg(64, 8), blk(256);
    gemm_bias<<<gg, blk, 0, stream>>>(x, Wq, bq, qkbuf, 0);
    gemm_bias<<<gg, blk, 0, stream>>>(x, Wv, bv, vbuf, 0);
    hash_kernel<<<8192, 256, 0, stream>>>(qkbuf, hv, loc2);
    sort_kernel<<<64, 64, 0, stream>>>(loc2, stbuf);
    attn_kernel<<<2048, 256, 0, stream>>>(qkbuf, vbuf, loc2, stbuf, lseg, vog);
    combine_kernel<<<8192, 256, 0, stream>>>(vog, lseg, att);
    gemm_bias<<<gg, blk, 0, stream>>>(att, Wo, bo, (float*)d_out, 1);
}

// Round 4
// 270.506 us; speedup vs baseline: 2.5665x; 1.2317x over previous
//
#include <hip/hip_runtime.h>
#include <hip/hip_bf16.h>
#include <math.h>

// Problem constants (b=2, s=2048, d=512, h=8, k=64, rounds=4, buckets=32, cs=64)
#define WS_ 192          // 3 * 64 (acn=1 window)
#define NEGF (-3.402823466e+38f)

typedef __attribute__((ext_vector_type(8))) short short8;
typedef __attribute__((ext_vector_type(4))) float f32x4;
typedef __attribute__((ext_vector_type(4))) unsigned int u32x4;

static __device__ __forceinline__ unsigned int f2bf(float f) {
    unsigned int u = __float_as_uint(f);
    return (u + 0x7FFFu + ((u >> 16) & 1u)) >> 16;
}
// pack f32 into (hi bf16 | lo bf16<<16), hi+lo ~ exact (rel err ~2^-18)
static __device__ __forceinline__ unsigned int packsplit(float v) {
    unsigned int h = f2bf(v);
    float hf = __uint_as_float(h << 16);
    unsigned int l = f2bf(v - hf);
    return h | (l << 16);
}
// split packed uint4-pair into hi/lo bf16 fragments via v_perm
static __device__ __forceinline__ void mkfrag(uint4 a, uint4 b, short8 &h, short8 &l) {
    u32x4 hv, lv;
    hv[0] = __builtin_amdgcn_perm(a.y, a.x, 0x05040100u);
    hv[1] = __builtin_amdgcn_perm(a.w, a.z, 0x05040100u);
    hv[2] = __builtin_amdgcn_perm(b.y, b.x, 0x05040100u);
    hv[3] = __builtin_amdgcn_perm(b.w, b.z, 0x05040100u);
    lv[0] = __builtin_amdgcn_perm(a.y, a.x, 0x07060302u);
    lv[1] = __builtin_amdgcn_perm(a.w, a.z, 0x07060302u);
    lv[2] = __builtin_amdgcn_perm(b.y, b.x, 0x07060302u);
    lv[3] = __builtin_amdgcn_perm(b.w, b.z, 0x07060302u);
    h = __builtin_bit_cast(short8, hv);
    l = __builtin_bit_cast(short8, lv);
}
static __device__ __forceinline__ unsigned int cvtpk(float lo, float hi) {
    unsigned int d;
    asm("v_cvt_pk_bf16_f32 %0, %1, %2" : "=v"(d) : "v"(lo), "v"(hi));
    return d;
}

// ---------------------------------------------------------------------------
// pack kernel: xpk = split(x); wvT/woT = split(W^T)
// ---------------------------------------------------------------------------
__global__ __launch_bounds__(256) void pack_kernel(const float* __restrict__ x,
                                                   const float* __restrict__ Wv,
                                                   const float* __restrict__ Wo,
                                                   unsigned int* __restrict__ xpk,
                                                   unsigned int* __restrict__ wvT,
                                                   unsigned int* __restrict__ woT) {
    int idx = blockIdx.x * 256 + threadIdx.x;
    if (idx < 2097152) { xpk[idx] = packsplit(x[idx]); return; }
    idx -= 2097152;
    if (idx < 262144) {
        int k = idx >> 9, n = idx & 511;
        wvT[n * 512 + k] = packsplit(Wv[idx]);
        return;
    }
    idx -= 262144;
    int k = idx >> 9, n = idx & 511;
    woT[n * 512 + k] = packsplit(Wo[idx]);
}

// ---------------------------------------------------------------------------
// f32 GEMM for qk (hash feeds argmax -> must stay f32-accurate).
// Epilogue: qkbuf f32 (b,h,s,k), qkpk packed split, scaleQ = 0.125/||row||.
// ---------------------------------------------------------------------------
__global__ __launch_bounds__(256) void gemm_f32qk(const float* __restrict__ A,
                                                  const float* __restrict__ W,
                                                  const float* __restrict__ bias,
                                                  float* __restrict__ C,
                                                  unsigned int* __restrict__ Cpk,
                                                  float* __restrict__ scaleQ) {
    __shared__ float As[32][68];
    __shared__ float Ws[32][68];
    const int m0 = blockIdx.x * 64;
    const int n0 = blockIdx.y * 64;
    const int tid = threadIdx.x;
    const int ty = tid >> 4, tx = tid & 15;
    const int ci = tid & 7, ri = tid >> 3;
    const int wk = tid >> 4, wt = tid & 15;
    float acc[4][4] = {};
    for (int k0 = 0; k0 < 512; k0 += 32) {
#pragma unroll
        for (int h = 0; h < 2; ++h) {
            int i = ri + h * 32;
            float4 a4 = *(const float4*)(A + (size_t)(m0 + i) * 512 + k0 + ci * 4);
            As[ci * 4 + 0][i] = a4.x;
            As[ci * 4 + 1][i] = a4.y;
            As[ci * 4 + 2][i] = a4.z;
            As[ci * 4 + 3][i] = a4.w;
        }
#pragma unroll
        for (int h = 0; h < 2; ++h) {
            int kk = wk + h * 16;
            float4 w4 = *(const float4*)(W + (size_t)(k0 + kk) * 512 + n0 + wt * 4);
            *(float4*)(&Ws[kk][wt * 4]) = w4;
        }
        __syncthreads();
#pragma unroll
        for (int kk = 0; kk < 32; ++kk) {
            float4 a4 = *(float4*)(&As[kk][ty * 4]);
            float4 w4 = *(float4*)(&Ws[kk][tx * 4]);
            float a[4] = {a4.x, a4.y, a4.z, a4.w};
            float w[4] = {w4.x, w4.y, w4.z, w4.w};
#pragma unroll
            for (int i = 0; i < 4; ++i)
#pragma unroll
                for (int j = 0; j < 4; ++j) acc[i][j] += a[i] * w[j];
        }
        __syncthreads();
    }
    const int h = n0 >> 6;
#pragma unroll
    for (int i = 0; i < 4; ++i) {
        int m = m0 + ty * 4 + i;
        int b = m >> 11, s = m & 2047;
        float v0 = acc[i][0] + bias[n0 + tx * 4 + 0];
        float v1 = acc[i][1] + bias[n0 + tx * 4 + 1];
        float v2 = acc[i][2] + bias[n0 + tx * 4 + 2];
        float v3 = acc[i][3] + bias[n0 + tx * 4 + 3];
        size_t base = ((size_t)(((b << 3) + h) * 2048 + s)) * 64 + tx * 4;
        *(float4*)(C + base) = make_float4(v0, v1, v2, v3);
        uint4 pk = make_uint4(packsplit(v0), packsplit(v1), packsplit(v2), packsplit(v3));
        *(uint4*)(Cpk + base) = pk;
        float sq = v0 * v0 + v1 * v1 + v2 * v2 + v3 * v3;
        sq += __shfl_xor(sq, 1, 16); sq += __shfl_xor(sq, 2, 16);
        sq += __shfl_xor(sq, 4, 16); sq += __shfl_xor(sq, 8, 16);
        if (tx == 0)
            scaleQ[(size_t)(((b << 3) + h) * 2048 + s)] = 0.125f / fmaxf(sqrtf(sq), 1e-12f);
    }
}

// ---------------------------------------------------------------------------
// split-bf16 MFMA GEMM (3-term): C = A(4096x512,packed) @ B^T-tile + bias.
// mode 0: write bf16 to (b,h,s,k) layout (v path); mode 1: f32 row-major.
// ---------------------------------------------------------------------------
__global__ __launch_bounds__(256) void gemm_pk(const unsigned int* __restrict__ Apk,
                                               const unsigned int* __restrict__ BT,
                                               const float* __restrict__ bias,
                                               void* __restrict__ Cout, int mode) {
    __shared__ __align__(16) unsigned int As[64 * 32];
    __shared__ __align__(16) unsigned int Bs[64 * 32];
    const int m0 = blockIdx.x * 64;
    const int n0 = blockIdx.y * 64;
    const int tid = threadIdx.x;
    const int lane = tid & 63, wv = tid >> 6;
    const int lx = lane & 15, hi = lane >> 4;
    f32x4 acc[4] = {{0.f,0.f,0.f,0.f},{0.f,0.f,0.f,0.f},{0.f,0.f,0.f,0.f},{0.f,0.f,0.f,0.f}};
    for (int k0 = 0; k0 < 512; k0 += 32) {
#pragma unroll
        for (int u = 0; u < 2; ++u) {
            int qi = u * 256 + tid;
            int row = qi >> 3, qd = qi & 7;
            uint4 a = *(const uint4*)(Apk + (size_t)(m0 + row) * 512 + k0 + qd * 4);
            *(uint4*)(&As[row * 32 + ((qd ^ (row & 7)) << 2)]) = a;
            uint4 b = *(const uint4*)(BT + (size_t)(n0 + row) * 512 + k0 + qd * 4);
            *(uint4*)(&Bs[row * 32 + ((qd ^ (row & 7)) << 2)]) = b;
        }
        __syncthreads();
        int arow = wv * 16 + lx;
        uint4 a0 = *(uint4*)(&As[arow * 32 + (((2 * hi) ^ (arow & 7)) << 2)]);
        uint4 a1 = *(uint4*)(&As[arow * 32 + (((2 * hi + 1) ^ (arow & 7)) << 2)]);
        short8 Ah, Al; mkfrag(a0, a1, Ah, Al);
#pragma unroll
        for (int j = 0; j < 4; ++j) {
            int brow = j * 16 + lx;
            uint4 b0 = *(uint4*)(&Bs[brow * 32 + (((2 * hi) ^ (brow & 7)) << 2)]);
            uint4 b1 = *(uint4*)(&Bs[brow * 32 + (((2 * hi + 1) ^ (brow & 7)) << 2)]);
            short8 Bh2, Bl2; mkfrag(b0, b1, Bh2, Bl2);
            acc[j] = __builtin_amdgcn_mfma_f32_16x16x32_bf16(Ah, Bh2, acc[j], 0, 0, 0);
            acc[j] = __builtin_amdgcn_mfma_f32_16x16x32_bf16(Ah, Bl2, acc[j], 0, 0, 0);
            acc[j] = __builtin_amdgcn_mfma_f32_16x16x32_bf16(Al, Bh2, acc[j], 0, 0, 0);
        }
        __syncthreads();
    }
#pragma unroll
    for (int j = 0; j < 4; ++j) {
        int nn = n0 + j * 16 + lx;
        float bs = bias[nn];
#pragma unroll
        for (int reg = 0; reg < 4; ++reg) {
            int m = m0 + wv * 16 + hi * 4 + reg;
            float val = acc[j][reg] + bs;
            if (mode == 0) {
                int b = m >> 11, ss = m & 2047;
                int hh = nn >> 6, f = nn & 63;
                ((unsigned short*)Cout)[((size_t)(((b << 3) + hh) * 2048 + ss)) * 64 + f] =
                    (unsigned short)f2bf(val);
            } else {
                ((float*)Cout)[(size_t)m * 512 + nn] = val;
            }
        }
    }
}

// ---------------------------------------------------------------------------
// LSH hashing v2: LDS-tiled. Per block: one (b,h) x 64-token tile.
// rot(64x64) = qk_tile(64x64) @ hvr(64x64); argmax over concat(-rot,rot).
// ---------------------------------------------------------------------------
__global__ __launch_bounds__(256) void hash_kernel(const float* __restrict__ qk,
                                                   const float* __restrict__ hv,
                                                   int* __restrict__ loc2) {
    __shared__ float HS[64 * 68];   // [k][vr]
    __shared__ float QS[64 * 68];   // [tok][k] -> reused as rot [tok][vr]
    const int bh = blockIdx.x >> 5;
    const int t0 = (blockIdx.x & 31) * 64;
    const int h = bh & 7;
    const int tid = threadIdx.x;
#pragma unroll
    for (int u = 0; u < 4; ++u) {
        int idx = (u * 256 + tid) * 4;
        int k = idx >> 6, vr = idx & 63;
        float4 v = *(const float4*)(hv + (size_t)h * 4096 + idx);
        *(float4*)(&HS[k * 68 + vr]) = v;
        int t = k;  // same decomposition for qk tile
        float4 q = *(const float4*)(qk + ((size_t)(bh * 2048) + t0 + t) * 64 + vr);
        *(float4*)(&QS[t * 68 + vr]) = q;
    }
    __syncthreads();
    const int vr = tid & 63, tg = tid >> 6;
    float rot[16];
#pragma unroll
    for (int i = 0; i < 16; ++i) rot[i] = 0.f;
    for (int k = 0; k < 64; ++k) {
        float hvv = HS[k * 68 + vr];
#pragma unroll
        for (int i = 0; i < 16; ++i) rot[i] += QS[(tg * 16 + i) * 68 + k] * hvv;
    }
    __syncthreads();
#pragma unroll
    for (int i = 0; i < 16; ++i) QS[(tg * 16 + i) * 68 + vr] = rot[i];
    __syncthreads();
    const int tok = tid >> 2, rr = tid & 3;
    float best = -QS[tok * 68 + rr];
    int bj = 0;
    for (int j = 1; j < 16; ++j) {
        float v = QS[tok * 68 + j * 4 + rr];
        if (-v > best) { best = -v; bj = j; }
    }
    for (int j = 0; j < 16; ++j) {
        float v = QS[tok * 68 + j * 4 + rr];
        if (v > best) { best = v; bj = 16 + j; }
    }
    loc2[((size_t)(bh * 2048) + t0 + tok) * 4 + rr] = bj;
}

// ---------------------------------------------------------------------------
// Stable counting sort per (b,h,r), one wave per block, ballot-ranked.
// ---------------------------------------------------------------------------
__global__ __launch_bounds__(64) void sort_kernel(const int* __restrict__ loc2,
                                                  int* __restrict__ st) {
    __shared__ int base[32];
    __shared__ int cnt[32];
    const int gid = blockIdx.x;       // = bh*4 + r
    const int r = gid & 3, bh = gid >> 2;
    const int lane = threadIdx.x;
    if (lane < 32) { base[lane] = 0; cnt[lane] = 0; }
    __syncthreads();
    for (int chunk = 0; chunk < 32; ++chunk) {
        int b = loc2[(size_t)(bh * 2048 + chunk * 64 + lane) * 4 + r];
        atomicAdd(&base[b], 1);
    }
    __syncthreads();
    if (lane == 0) {
        int acc = 0;
        for (int k = 0; k < 32; ++k) { int h = base[k]; base[k] = acc; acc += h; }
    }
    __syncthreads();
    const unsigned long long lower_mask = (lane == 0) ? 0ull : ((~0ull) >> (64 - lane));
    for (int chunk = 0; chunk < 32; ++chunk) {
        int p = chunk * 64 + lane;
        int b = loc2[(size_t)(bh * 2048 + p) * 4 + r];
#pragma unroll 1
        for (int bkt = 0; bkt < 32; ++bkt) {
            unsigned long long m = __ballot(b == bkt);
            if (b == bkt) {
                int lower = __popcll(m & lower_mask);
                int rank = base[bkt] + cnt[bkt] + lower;
                st[(size_t)gid * 2048 + rank] = p;
                if (lower == 0) cnt[bkt] += (int)__popcll(m);
            }
        }
    }
}

// ---------------------------------------------------------------------------
// Chunked attention v4.
// QK^T: split-bf16 3-term MFMA from pre-packed qkpk (swapped: S^T = K Q^T).
// PV: plain-bf16 MFMA; P[q][c] and V^T[f][c] staged bf16 in reused LDS.
// ---------------------------------------------------------------------------
#define KQUAD(row, qd) (((row) << 6) + ((((qd) ^ ((row) & 15))) << 2))
#define PBASE 6400

__global__ __launch_bounds__(256, 3) void attn_kernel(const unsigned int* __restrict__ qkpk,
                                                      const unsigned short* __restrict__ vpk,
                                                      const float* __restrict__ scaleQ,
                                                      const int* __restrict__ loc2,
                                                      const int* __restrict__ st,
                                                      float* __restrict__ lseg,
                                                      float* __restrict__ vog) {
    __shared__ __align__(16) unsigned int U[12800];  // K (12288) -> V^T + P
    __shared__ float scaleK[WS_];
    __shared__ int Tk[WS_];
    __shared__ int Lp[WS_];

    const int gid = blockIdx.x;
    const int n = gid & 31;
    const int r = (gid >> 5) & 3;
    const int bh = gid >> 7;
    const int tid = threadIdx.x;
    const int sbase = (bh * 4 + r) * 2048;
    const int lane = tid & 63;
    const int wv = tid >> 6;
    const int lx = lane & 15;
    const int hi = lane >> 4;

    if (tid < WS_) {
        int w = tid;
        int chunk = (n + 31 + (w >> 6)) & 31;
        int t = st[(size_t)sbase + chunk * 64 + (w & 63)];
        Tk[w] = t;
        int4 l4 = *(const int4*)(loc2 + (size_t)(bh * 2048 + t) * 4);
        Lp[w] = l4.x | (l4.y << 8) | (l4.z << 16) | (l4.w << 24);
        scaleK[w] = scaleQ[bh * 2048 + t];
    }
    __syncthreads();

    // ---- stage K (pre-packed)
    const int fs = tid & 15, wsb = tid >> 4;
#pragma unroll
    for (int it = 0; it < 12; ++it) {
        int row = it * 16 + wsb;
        uint4 v4 = *(const uint4*)(qkpk + ((size_t)(bh * 2048 + Tk[row])) * 64 + fs * 4);
        *(uint4*)(&U[KQUAD(row, fs)]) = v4;
    }
    __syncthreads();

    // ---- QK^T (swapped): S^T[c][q]
    const int qw = 64 + wv * 16 + lx;
    short8 Bh[2], Bl[2];
#pragma unroll
    for (int ks = 0; ks < 2; ++ks) {
        int qd0 = ks * 8 + hi * 2;
        uint4 a = *(const uint4*)(&U[KQUAD(qw, qd0)]);
        uint4 b = *(const uint4*)(&U[KQUAD(qw, qd0 + 1)]);
        mkfrag(a, b, Bh[ks], Bl[ks]);
    }
    f32x4 s[12];
#pragma unroll
    for (int ct = 0; ct < 12; ++ct) {
        f32x4 acc = {0.f, 0.f, 0.f, 0.f};
#pragma unroll
        for (int ks = 0; ks < 2; ++ks) {
            int arow = ct * 16 + lx;
            int qd0 = ks * 8 + hi * 2;
            uint4 a = *(const uint4*)(&U[KQUAD(arow, qd0)]);
            uint4 b = *(const uint4*)(&U[KQUAD(arow, qd0 + 1)]);
            short8 Ah, Al; mkfrag(a, b, Ah, Al);
            acc = __builtin_amdgcn_mfma_f32_16x16x32_bf16(Ah, Bh[ks], acc, 0, 0, 0);
            acc = __builtin_amdgcn_mfma_f32_16x16x32_bf16(Ah, Bl[ks], acc, 0, 0, 0);
            acc = __builtin_amdgcn_mfma_f32_16x16x32_bf16(Al, Bh[ks], acc, 0, 0, 0);
        }
        s[ct] = acc;
    }

    // issue V loads early (hide HBM/L2 latency under softmax)
    uint4 vl0[3], vl1[3];
#pragma unroll
    for (int it = 0; it < 3; ++it) {
        int idx = it * 256 + tid;
        int pr = idx >> 3, oct = idx & 7;
        vl0[it] = *(const uint4*)(vpk + ((size_t)(bh * 2048 + Tk[pr * 2])) * 64 + oct * 8);
        vl1[it] = *(const uint4*)(vpk + ((size_t)(bh * 2048 + Tk[pr * 2 + 1])) * 64 + oct * 8);
    }
    __syncthreads();   // K reads done; U reusable

    // ---- masks + register softmax (lane owns q = qw, 48 c-values)
    const int lq = Lp[qw];
    const unsigned int bmask = 0x80u << (r * 8);
    float mx = -3.0e38f;
#pragma unroll
    for (int ct = 0; ct < 12; ++ct) {
#pragma unroll
        for (int rr = 0; rr < 4; ++rr) {
            int c = ct * 16 + hi * 4 + rr;
            float val = s[ct][rr] * scaleK[c];
            unsigned int x = (unsigned int)(lq ^ Lp[c]);
            unsigned int z = ((x & 0x7f7f7f7fu) + 0x7f7f7f7fu) | x;
            unsigned int zm = ~z & 0x80808080u;
            int dup = __popc(zm);
            val = (c == qw) ? -100000.0f : val;
            val = (zm & bmask) ? val : NEGF;
            val -= __logf((float)dup + 1e-9f);
            s[ct][rr] = val;
            mx = fmaxf(mx, val);
        }
    }
    mx = fmaxf(mx, __shfl_xor(mx, 16));
    mx = fmaxf(mx, __shfl_xor(mx, 32));
    float ssum = 0.f;
#pragma unroll
    for (int ct = 0; ct < 12; ++ct)
#pragma unroll
        for (int rr = 0; rr < 4; ++rr) {
            float e = __expf(s[ct][rr] - mx);
            s[ct][rr] = e;
            ssum += e;
        }
    ssum += __shfl_xor(ssum, 16);
    ssum += __shfl_xor(ssum, 32);
    float lse = mx + __logf(ssum);
    if (hi == 0) lseg[(size_t)sbase + Tk[qw]] = lse;
    float inv = 1.0f / ssum;

    // ---- stage V^T bf16 into U[0..6400) (stride 100 words, granule-XOR)
#pragma unroll
    for (int it = 0; it < 3; ++it) {
        int idx = it * 256 + tid;
        int pr = idx >> 3, oct = idx & 7;
        int c0 = pr * 2;
        unsigned int aw[4] = {vl0[it].x, vl0[it].y, vl0[it].z, vl0[it].w};
        unsigned int bw[4] = {vl1[it].x, vl1[it].y, vl1[it].z, vl1[it].w};
#pragma unroll
        for (int j = 0; j < 8; ++j) {
            int f = oct * 8 + j;
            unsigned int lo = (aw[j >> 1] >> ((j & 1) * 16)) & 0xffffu;
            unsigned int hh = (bw[j >> 1] >> ((j & 1) * 16)) & 0xffffu;
            U[f * 100 + ((((c0 >> 3) ^ (f & 7))) << 2) + ((c0 & 7) >> 1)] = lo | (hh << 16);
        }
    }
    // ---- P[q][c] bf16 into U[PBASE..): stride 100 words
    const int q = wv * 16 + lx;
#pragma unroll
    for (int ct = 0; ct < 12; ++ct) {
        U[PBASE + q * 100 + ct * 8 + hi * 2 + 0] = cvtpk(s[ct][0] * inv, s[ct][1] * inv);
        U[PBASE + q * 100 + ct * 8 + hi * 2 + 1] = cvtpk(s[ct][2] * inv, s[ct][3] * inv);
    }
    __syncthreads();

    // ---- PV: O^T[f][q] = V^T · P^T, single-MFMA bf16
    f32x4 o[4] = {{0.f,0.f,0.f,0.f},{0.f,0.f,0.f,0.f},{0.f,0.f,0.f,0.f},{0.f,0.f,0.f,0.f}};
    const unsigned short* Uh = (const unsigned short*)U;
#pragma unroll
    for (int ks = 0; ks < 6; ++ks) {
        short8 P8 = *(const short8*)(Uh + PBASE * 2 + q * 200 + ks * 32 + hi * 8);
#pragma unroll
        for (int ft = 0; ft < 4; ++ft) {
            int f = ft * 16 + lx;
            short8 V8 = *(const short8*)(Uh + f * 200 + ((((4 * ks + hi) ^ (f & 7))) << 3));
            o[ft] = __builtin_amdgcn_mfma_f32_16x16x32_bf16(V8, P8, o[ft], 0, 0, 0);
        }
    }
    const int tko = Tk[qw];
#pragma unroll
    for (int ft = 0; ft < 4; ++ft) {
        float4 w4 = make_float4(o[ft][0], o[ft][1], o[ft][2], o[ft][3]);
        *(float4*)(vog + ((size_t)sbase + tko) * 64 + ft * 16 + hi * 4) = w4;
    }
}

// ---------------------------------------------------------------------------
// Combine rounds -> packed split att (A of the Wo GEMM).
// ---------------------------------------------------------------------------
__global__ __launch_bounds__(256) void combine_kernel(const float* __restrict__ vog,
                                                      const float* __restrict__ lseg,
                                                      unsigned int* __restrict__ attpk) {
    const int gid = blockIdx.x * 256 + threadIdx.x;
    const int k = gid & 63;
    const int t = (gid >> 6) & 2047;
    const int bh = gid >> 17;
    const int b = bh >> 3, h = bh & 7;
    float l[4], vo[4];
#pragma unroll
    for (int r = 0; r < 4; ++r) {
        l[r] = lseg[(size_t)(bh * 4 + r) * 2048 + t];
        vo[r] = vog[((size_t)(bh * 4 + r) * 2048 + t) * 64 + k];
    }
    float m = fmaxf(fmaxf(l[0], l[1]), fmaxf(l[2], l[3]));
    float ss = expf(l[0] - m) + expf(l[1] - m) + expf(l[2] - m) + expf(l[3] - m);
    float lt = m + logf(ss);
    float out = 0.f;
#pragma unroll
    for (int r = 0; r < 4; ++r) out += expf(l[r] - lt) * vo[r];
    attpk[((size_t)(b * 2048 + t)) * 512 + h * 64 + k] = packsplit(out);
}

// ---------------------------------------------------------------------------
extern "C" void kernel_launch(void* const* d_in, const int* in_sizes, int n_in,
                              void* d_out, int out_size, void* d_ws, size_t ws_size,
                              hipStream_t stream) {
    const float* x  = (const float*)d_in[0];
    const float* Wq = (const float*)d_in[1];
    const float* bq = (const float*)d_in[2];
    const float* Wv = (const float*)d_in[3];
    const float* bv = (const float*)d_in[4];
    const float* Wo = (const float*)d_in[5];
    const float* bo = (const float*)d_in[6];
    const float* hv = (const float*)d_in[7];

    unsigned int* W = (unsigned int*)d_ws;
    float*          vog    = (float*)W;                         // [0, 8388608) f32
    float*          qkbuf  = (float*)W;                         // alias [0, 2097152) - dead after hash
    unsigned int*   xpk    = W + 2097152;                       // alias - dead after v-gemm
    unsigned int*   qkpk   = W + 8388608;                       // 2097152
    unsigned short* vpk    = (unsigned short*)(W + 10485760);   // 2097152 ushort (1M u32)
    unsigned int*   attpk  = W + 11534336;                      // 2097152
    float*          scaleQ = (float*)(W + 13631488);            // 32768
    int*            loc2   = (int*)(W + 13664256);              // 131072
    int*            stbuf  = (int*)(W + 13795328);              // 131072
    float*          lseg   = (float*)(W + 13926400);            // 131072
    unsigned int*   wvT    = W + 14057472;                      // 262144
    unsigned int*   woT    = W + 14319616;                      // 262144

    dim3 gg(64, 8), blk(256);
    pack_kernel<<<10240, 256, 0, stream>>>(x, Wv, Wo, xpk, wvT, woT);
    gemm_f32qk<<<gg, blk, 0, stream>>>(x, Wq, bq, qkbuf, qkpk, scaleQ);
    gemm_pk<<<gg, blk, 0, stream>>>(xpk, wvT, bv, (void*)vpk, 0);
    hash_kernel<<<512, 256, 0, stream>>>(qkbuf, hv, loc2);
    sort_kernel<<<64, 64, 0, stream>>>(loc2, stbuf);
    attn_kernel<<<2048, 256, 0, stream>>>(qkpk, vpk, scaleQ, loc2, stbuf, lseg, vog);
    combine_kernel<<<8192, 256, 0, stream>>>(vog, lseg, attpk);
    gemm_pk<<<gg, blk, 0, stream>>>(attpk, woT, bo, d_out, 1);
}

// Round 5
// 183.382 us; speedup vs baseline: 3.7859x; 1.4751x over previous
//
#include <hip/hip_runtime.h>
#include <hip/hip_bf16.h>
#include <math.h>

// Problem constants (b=2, s=2048, d=512, h=8, k=64, rounds=4, buckets=32, cs=64)
#define WS_ 192          // 3 * 64 (acn=1 window)
#define NEGF (-3.402823466e+38f)

typedef __attribute__((ext_vector_type(8))) short short8;
typedef __attribute__((ext_vector_type(4))) float f32x4;
typedef __attribute__((ext_vector_type(4))) unsigned int u32x4;

static __device__ __forceinline__ unsigned int f2bf(float f) {
    unsigned int u = __float_as_uint(f);
    return (u + 0x7FFFu + ((u >> 16) & 1u)) >> 16;
}
// pack f32 into (hi bf16 | lo bf16<<16), hi+lo ~ exact (rel err ~2^-18)
static __device__ __forceinline__ unsigned int packsplit(float v) {
    unsigned int h = f2bf(v);
    float hf = __uint_as_float(h << 16);
    unsigned int l = f2bf(v - hf);
    return h | (l << 16);
}
// split packed uint4-pair into hi/lo bf16 fragments via v_perm
static __device__ __forceinline__ void mkfrag(uint4 a, uint4 b, short8 &h, short8 &l) {
    u32x4 hv, lv;
    hv[0] = __builtin_amdgcn_perm(a.y, a.x, 0x05040100u);
    hv[1] = __builtin_amdgcn_perm(a.w, a.z, 0x05040100u);
    hv[2] = __builtin_amdgcn_perm(b.y, b.x, 0x05040100u);
    hv[3] = __builtin_amdgcn_perm(b.w, b.z, 0x05040100u);
    lv[0] = __builtin_amdgcn_perm(a.y, a.x, 0x07060302u);
    lv[1] = __builtin_amdgcn_perm(a.w, a.z, 0x07060302u);
    lv[2] = __builtin_amdgcn_perm(b.y, b.x, 0x07060302u);
    lv[3] = __builtin_amdgcn_perm(b.w, b.z, 0x07060302u);
    h = __builtin_bit_cast(short8, hv);
    l = __builtin_bit_cast(short8, lv);
}
static __device__ __forceinline__ unsigned int cvtpk(float lo, float hi) {
    unsigned int d;
    asm("v_cvt_pk_bf16_f32 %0, %1, %2" : "=v"(d) : "v"(lo), "v"(hi));
    return d;
}

// ---------------------------------------------------------------------------
// pack kernel: xpk = split(x); wvT/woT = split(W^T)
// ---------------------------------------------------------------------------
__global__ __launch_bounds__(256) void pack_kernel(const float* __restrict__ x,
                                                   const float* __restrict__ Wv,
                                                   const float* __restrict__ Wo,
                                                   unsigned int* __restrict__ xpk,
                                                   unsigned int* __restrict__ wvT,
                                                   unsigned int* __restrict__ woT) {
    int idx = blockIdx.x * 256 + threadIdx.x;
    if (idx < 2097152) { xpk[idx] = packsplit(x[idx]); return; }
    idx -= 2097152;
    if (idx < 262144) {
        int k = idx >> 9, n = idx & 511;
        wvT[n * 512 + k] = packsplit(Wv[idx]);
        return;
    }
    idx -= 262144;
    int k = idx >> 9, n = idx & 511;
    woT[n * 512 + k] = packsplit(Wo[idx]);
}

// ---------------------------------------------------------------------------
// f32 GEMM for qk (hash feeds argmax -> must stay f32-accurate).
// Epilogue: qkbuf f32 (b,h,s,k), qkpk packed split, scaleQ = 0.125/||row||.
// ---------------------------------------------------------------------------
__global__ __launch_bounds__(256) void gemm_f32qk(const float* __restrict__ A,
                                                  const float* __restrict__ W,
                                                  const float* __restrict__ bias,
                                                  float* __restrict__ C,
                                                  unsigned int* __restrict__ Cpk,
                                                  float* __restrict__ scaleQ) {
    __shared__ float As[32][68];
    __shared__ float Ws[32][68];
    const int m0 = blockIdx.x * 64;
    const int n0 = blockIdx.y * 64;
    const int tid = threadIdx.x;
    const int ty = tid >> 4, tx = tid & 15;
    const int ci = tid & 7, ri = tid >> 3;
    const int wk = tid >> 4, wt = tid & 15;
    float acc[4][4] = {};
    for (int k0 = 0; k0 < 512; k0 += 32) {
#pragma unroll
        for (int h = 0; h < 2; ++h) {
            int i = ri + h * 32;
            float4 a4 = *(const float4*)(A + (size_t)(m0 + i) * 512 + k0 + ci * 4);
            As[ci * 4 + 0][i] = a4.x;
            As[ci * 4 + 1][i] = a4.y;
            As[ci * 4 + 2][i] = a4.z;
            As[ci * 4 + 3][i] = a4.w;
        }
#pragma unroll
        for (int h = 0; h < 2; ++h) {
            int kk = wk + h * 16;
            float4 w4 = *(const float4*)(W + (size_t)(k0 + kk) * 512 + n0 + wt * 4);
            *(float4*)(&Ws[kk][wt * 4]) = w4;
        }
        __syncthreads();
#pragma unroll
        for (int kk = 0; kk < 32; ++kk) {
            float4 a4 = *(float4*)(&As[kk][ty * 4]);
            float4 w4 = *(float4*)(&Ws[kk][tx * 4]);
            float a[4] = {a4.x, a4.y, a4.z, a4.w};
            float w[4] = {w4.x, w4.y, w4.z, w4.w};
#pragma unroll
            for (int i = 0; i < 4; ++i)
#pragma unroll
                for (int j = 0; j < 4; ++j) acc[i][j] += a[i] * w[j];
        }
        __syncthreads();
    }
    const int h = n0 >> 6;
#pragma unroll
    for (int i = 0; i < 4; ++i) {
        int m = m0 + ty * 4 + i;
        int b = m >> 11, s = m & 2047;
        float v0 = acc[i][0] + bias[n0 + tx * 4 + 0];
        float v1 = acc[i][1] + bias[n0 + tx * 4 + 1];
        float v2 = acc[i][2] + bias[n0 + tx * 4 + 2];
        float v3 = acc[i][3] + bias[n0 + tx * 4 + 3];
        size_t base = ((size_t)(((b << 3) + h) * 2048 + s)) * 64 + tx * 4;
        *(float4*)(C + base) = make_float4(v0, v1, v2, v3);
        uint4 pk = make_uint4(packsplit(v0), packsplit(v1), packsplit(v2), packsplit(v3));
        *(uint4*)(Cpk + base) = pk;
        float sq = v0 * v0 + v1 * v1 + v2 * v2 + v3 * v3;
        sq += __shfl_xor(sq, 1, 16); sq += __shfl_xor(sq, 2, 16);
        sq += __shfl_xor(sq, 4, 16); sq += __shfl_xor(sq, 8, 16);
        if (tx == 0)
            scaleQ[(size_t)(((b << 3) + h) * 2048 + s)] = 0.125f / fmaxf(sqrtf(sq), 1e-12f);
    }
}

// ---------------------------------------------------------------------------
// split-bf16 MFMA GEMM (3-term): C = A(4096x512,packed) @ B^T-tile + bias.
// mode 0: write bf16 to (b,h,s,k) layout (v path); mode 1: f32 row-major.
// ---------------------------------------------------------------------------
__global__ __launch_bounds__(256) void gemm_pk(const unsigned int* __restrict__ Apk,
                                               const unsigned int* __restrict__ BT,
                                               const float* __restrict__ bias,
                                               void* __restrict__ Cout, int mode) {
    __shared__ __align__(16) unsigned int As[64 * 32];
    __shared__ __align__(16) unsigned int Bs[64 * 32];
    const int m0 = blockIdx.x * 64;
    const int n0 = blockIdx.y * 64;
    const int tid = threadIdx.x;
    const int lane = tid & 63, wv = tid >> 6;
    const int lx = lane & 15, hi = lane >> 4;
    f32x4 acc[4] = {{0.f,0.f,0.f,0.f},{0.f,0.f,0.f,0.f},{0.f,0.f,0.f,0.f},{0.f,0.f,0.f,0.f}};
    for (int k0 = 0; k0 < 512; k0 += 32) {
#pragma unroll
        for (int u = 0; u < 2; ++u) {
            int qi = u * 256 + tid;
            int row = qi >> 3, qd = qi & 7;
            uint4 a = *(const uint4*)(Apk + (size_t)(m0 + row) * 512 + k0 + qd * 4);
            *(uint4*)(&As[row * 32 + ((qd ^ (row & 7)) << 2)]) = a;
            uint4 b = *(const uint4*)(BT + (size_t)(n0 + row) * 512 + k0 + qd * 4);
            *(uint4*)(&Bs[row * 32 + ((qd ^ (row & 7)) << 2)]) = b;
        }
        __syncthreads();
        int arow = wv * 16 + lx;
        uint4 a0 = *(uint4*)(&As[arow * 32 + (((2 * hi) ^ (arow & 7)) << 2)]);
        uint4 a1 = *(uint4*)(&As[arow * 32 + (((2 * hi + 1) ^ (arow & 7)) << 2)]);
        short8 Ah, Al; mkfrag(a0, a1, Ah, Al);
#pragma unroll
        for (int j = 0; j < 4; ++j) {
            int brow = j * 16 + lx;
            uint4 b0 = *(uint4*)(&Bs[brow * 32 + (((2 * hi) ^ (brow & 7)) << 2)]);
            uint4 b1 = *(uint4*)(&Bs[brow * 32 + (((2 * hi + 1) ^ (brow & 7)) << 2)]);
            short8 Bh2, Bl2; mkfrag(b0, b1, Bh2, Bl2);
            acc[j] = __builtin_amdgcn_mfma_f32_16x16x32_bf16(Ah, Bh2, acc[j], 0, 0, 0);
            acc[j] = __builtin_amdgcn_mfma_f32_16x16x32_bf16(Ah, Bl2, acc[j], 0, 0, 0);
            acc[j] = __builtin_amdgcn_mfma_f32_16x16x32_bf16(Al, Bh2, acc[j], 0, 0, 0);
        }
        __syncthreads();
    }
#pragma unroll
    for (int j = 0; j < 4; ++j) {
        int nn = n0 + j * 16 + lx;
        float bs = bias[nn];
#pragma unroll
        for (int reg = 0; reg < 4; ++reg) {
            int m = m0 + wv * 16 + hi * 4 + reg;
            float val = acc[j][reg] + bs;
            if (mode == 0) {
                int b = m >> 11, ss = m & 2047;
                int hh = nn >> 6, f = nn & 63;
                ((unsigned short*)Cout)[((size_t)(((b << 3) + hh) * 2048 + ss)) * 64 + f] =
                    (unsigned short)f2bf(val);
            } else {
                ((float*)Cout)[(size_t)m * 512 + nn] = val;
            }
        }
    }
}

// ---------------------------------------------------------------------------
// LSH hashing v2: LDS-tiled. Per block: one (b,h) x 64-token tile.
// ---------------------------------------------------------------------------
__global__ __launch_bounds__(256) void hash_kernel(const float* __restrict__ qk,
                                                   const float* __restrict__ hv,
                                                   int* __restrict__ loc2) {
    __shared__ float HS[64 * 68];   // [k][vr]
    __shared__ float QS[64 * 68];   // [tok][k] -> reused as rot [tok][vr]
    const int bh = blockIdx.x >> 5;
    const int t0 = (blockIdx.x & 31) * 64;
    const int h = bh & 7;
    const int tid = threadIdx.x;
#pragma unroll
    for (int u = 0; u < 4; ++u) {
        int idx = (u * 256 + tid) * 4;
        int k = idx >> 6, vr = idx & 63;
        float4 v = *(const float4*)(hv + (size_t)h * 4096 + idx);
        *(float4*)(&HS[k * 68 + vr]) = v;
        int t = k;
        float4 q = *(const float4*)(qk + ((size_t)(bh * 2048) + t0 + t) * 64 + vr);
        *(float4*)(&QS[t * 68 + vr]) = q;
    }
    __syncthreads();
    const int vr = tid & 63, tg = tid >> 6;
    float rot[16];
#pragma unroll
    for (int i = 0; i < 16; ++i) rot[i] = 0.f;
    for (int k = 0; k < 64; ++k) {
        float hvv = HS[k * 68 + vr];
#pragma unroll
        for (int i = 0; i < 16; ++i) rot[i] += QS[(tg * 16 + i) * 68 + k] * hvv;
    }
    __syncthreads();
#pragma unroll
    for (int i = 0; i < 16; ++i) QS[(tg * 16 + i) * 68 + vr] = rot[i];
    __syncthreads();
    const int tok = tid >> 2, rr = tid & 3;
    float best = -QS[tok * 68 + rr];
    int bj = 0;
    for (int j = 1; j < 16; ++j) {
        float v = QS[tok * 68 + j * 4 + rr];
        if (-v > best) { best = -v; bj = j; }
    }
    for (int j = 0; j < 16; ++j) {
        float v = QS[tok * 68 + j * 4 + rr];
        if (v > best) { best = v; bj = 16 + j; }
    }
    loc2[((size_t)(bh * 2048) + t0 + tok) * 4 + rr] = bj;
}

// ---------------------------------------------------------------------------
// Stable counting sort v3: one 1024-thread block per (b,h,r); 16 waves,
// 2 segments of 64 tokens each.  Phase 1: per-segment histogram + stable
// in-segment rank via ballots (parallel across waves).  Phase 2: LDS prefix
// (seg-major per bucket, then bucket bases).  Phase 3: ranked scatter.
// ---------------------------------------------------------------------------
__global__ __launch_bounds__(1024) void sort_kernel(const int* __restrict__ loc2,
                                                    int* __restrict__ st) {
    __shared__ int hist[32][32];   // [seg][bkt]
    __shared__ int off[32][32];    // exclusive prefix over segs, per bkt
    __shared__ int base[32];       // exclusive prefix over buckets
    const int gid = blockIdx.x;    // = bh*4 + r
    const int r = gid & 3, bh = gid >> 2;
    const int tid = threadIdx.x;
    const int lane = tid & 63, wvi = tid >> 6;   // 16 waves
    const unsigned long long lower_mask =
        (lane == 0) ? 0ull : ((~0ull) >> (64 - lane));

    int myb[2], myrank[2];
#pragma unroll
    for (int si = 0; si < 2; ++si) {
        int seg = wvi * 2 + si;
        int p = seg * 64 + lane;
        int b = loc2[(size_t)(bh * 2048 + p) * 4 + r];
        myb[si] = b;
        myrank[si] = 0;
#pragma unroll 1
        for (int bkt = 0; bkt < 32; ++bkt) {
            unsigned long long m = __ballot(b == bkt);
            if (b == bkt) myrank[si] = __popcll(m & lower_mask);
            if (lane == bkt) hist[seg][bkt] = __popcll(m);
        }
    }
    __syncthreads();
    if (tid < 32) {   // per-bucket running prefix over segments
        int running = 0;
#pragma unroll 1
        for (int seg = 0; seg < 32; ++seg) {
            off[seg][tid] = running;
            running += hist[seg][tid];
        }
        base[tid] = running;      // column totals
    }
    __syncthreads();
    if (tid == 0) {               // exclusive prefix over buckets
        int acc = 0;
#pragma unroll 1
        for (int b = 0; b < 32; ++b) { int h = base[b]; base[b] = acc; acc += h; }
    }
    __syncthreads();
#pragma unroll
    for (int si = 0; si < 2; ++si) {
        int seg = wvi * 2 + si;
        int p = seg * 64 + lane;
        int b = myb[si];
        st[(size_t)gid * 2048 + base[b] + off[seg][b] + myrank[si]] = p;
    }
}

// ---------------------------------------------------------------------------
// Chunked attention v4.
// QK^T: split-bf16 3-term MFMA from pre-packed qkpk (swapped: S^T = K Q^T).
// PV: plain-bf16 MFMA; P[q][c] and V^T[f][c] staged bf16 in reused LDS.
// ---------------------------------------------------------------------------
#define KQUAD(row, qd) (((row) << 6) + ((((qd) ^ ((row) & 15))) << 2))
#define PBASE 6400

__global__ __launch_bounds__(256, 3) void attn_kernel(const unsigned int* __restrict__ qkpk,
                                                      const unsigned short* __restrict__ vpk,
                                                      const float* __restrict__ scaleQ,
                                                      const int* __restrict__ loc2,
                                                      const int* __restrict__ st,
                                                      float* __restrict__ lseg,
                                                      float* __restrict__ vog) {
    __shared__ __align__(16) unsigned int U[12800];  // K (12288) -> V^T + P
    __shared__ float scaleK[WS_];
    __shared__ int Tk[WS_];
    __shared__ int Lp[WS_];

    const int gid = blockIdx.x;
    const int n = gid & 31;
    const int r = (gid >> 5) & 3;
    const int bh = gid >> 7;
    const int tid = threadIdx.x;
    const int sbase = (bh * 4 + r) * 2048;
    const int lane = tid & 63;
    const int wv = tid >> 6;
    const int lx = lane & 15;
    const int hi = lane >> 4;

    if (tid < WS_) {
        int w = tid;
        int chunk = (n + 31 + (w >> 6)) & 31;
        int t = st[(size_t)sbase + chunk * 64 + (w & 63)];
        Tk[w] = t;
        int4 l4 = *(const int4*)(loc2 + (size_t)(bh * 2048 + t) * 4);
        Lp[w] = l4.x | (l4.y << 8) | (l4.z << 16) | (l4.w << 24);
        scaleK[w] = scaleQ[bh * 2048 + t];
    }
    __syncthreads();

    // ---- stage K (pre-packed)
    const int fs = tid & 15, wsb = tid >> 4;
#pragma unroll
    for (int it = 0; it < 12; ++it) {
        int row = it * 16 + wsb;
        uint4 v4 = *(const uint4*)(qkpk + ((size_t)(bh * 2048 + Tk[row])) * 64 + fs * 4);
        *(uint4*)(&U[KQUAD(row, fs)]) = v4;
    }
    __syncthreads();

    // ---- QK^T (swapped): S^T[c][q]
    const int qw = 64 + wv * 16 + lx;
    short8 Bh[2], Bl[2];
#pragma unroll
    for (int ks = 0; ks < 2; ++ks) {
        int qd0 = ks * 8 + hi * 2;
        uint4 a = *(const uint4*)(&U[KQUAD(qw, qd0)]);
        uint4 b = *(const uint4*)(&U[KQUAD(qw, qd0 + 1)]);
        mkfrag(a, b, Bh[ks], Bl[ks]);
    }
    f32x4 s[12];
#pragma unroll
    for (int ct = 0; ct < 12; ++ct) {
        f32x4 acc = {0.f, 0.f, 0.f, 0.f};
#pragma unroll
        for (int ks = 0; ks < 2; ++ks) {
            int arow = ct * 16 + lx;
            int qd0 = ks * 8 + hi * 2;
            uint4 a = *(const uint4*)(&U[KQUAD(arow, qd0)]);
            uint4 b = *(const uint4*)(&U[KQUAD(arow, qd0 + 1)]);
            short8 Ah, Al; mkfrag(a, b, Ah, Al);
            acc = __builtin_amdgcn_mfma_f32_16x16x32_bf16(Ah, Bh[ks], acc, 0, 0, 0);
            acc = __builtin_amdgcn_mfma_f32_16x16x32_bf16(Ah, Bl[ks], acc, 0, 0, 0);
            acc = __builtin_amdgcn_mfma_f32_16x16x32_bf16(Al, Bh[ks], acc, 0, 0, 0);
        }
        s[ct] = acc;
    }

    // issue V loads early (hide HBM/L2 latency under softmax)
    uint4 vl0[3], vl1[3];
#pragma unroll
    for (int it = 0; it < 3; ++it) {
        int idx = it * 256 + tid;
        int pr = idx >> 3, oct = idx & 7;
        vl0[it] = *(const uint4*)(vpk + ((size_t)(bh * 2048 + Tk[pr * 2])) * 64 + oct * 8);
        vl1[it] = *(const uint4*)(vpk + ((size_t)(bh * 2048 + Tk[pr * 2 + 1])) * 64 + oct * 8);
    }
    __syncthreads();   // K reads done; U reusable

    // ---- masks + register softmax (lane owns q = qw, 48 c-values)
    const int lq = Lp[qw];
    const unsigned int bmask = 0x80u << (r * 8);
    float mx = -3.0e38f;
#pragma unroll
    for (int ct = 0; ct < 12; ++ct) {
#pragma unroll
        for (int rr = 0; rr < 4; ++rr) {
            int c = ct * 16 + hi * 4 + rr;
            float val = s[ct][rr] * scaleK[c];
            unsigned int x = (unsigned int)(lq ^ Lp[c]);
            unsigned int z = ((x & 0x7f7f7f7fu) + 0x7f7f7f7fu) | x;
            unsigned int zm = ~z & 0x80808080u;
            int dup = __popc(zm);
            val = (c == qw) ? -100000.0f : val;
            val = (zm & bmask) ? val : NEGF;
            val -= __logf((float)dup + 1e-9f);
            s[ct][rr] = val;
            mx = fmaxf(mx, val);
        }
    }
    mx = fmaxf(mx, __shfl_xor(mx, 16));
    mx = fmaxf(mx, __shfl_xor(mx, 32));
    float ssum = 0.f;
#pragma unroll
    for (int ct = 0; ct < 12; ++ct)
#pragma unroll
        for (int rr = 0; rr < 4; ++rr) {
            float e = __expf(s[ct][rr] - mx);
            s[ct][rr] = e;
            ssum += e;
        }
    ssum += __shfl_xor(ssum, 16);
    ssum += __shfl_xor(ssum, 32);
    float lse = mx + __logf(ssum);
    if (hi == 0) lseg[(size_t)sbase + Tk[qw]] = lse;
    float inv = 1.0f / ssum;

    // ---- stage V^T bf16 into U[0..6400) (stride 100 words, granule-XOR)
#pragma unroll
    for (int it = 0; it < 3; ++it) {
        int idx = it * 256 + tid;
        int pr = idx >> 3, oct = idx & 7;
        int c0 = pr * 2;
        unsigned int aw[4] = {vl0[it].x, vl0[it].y, vl0[it].z, vl0[it].w};
        unsigned int bw[4] = {vl1[it].x, vl1[it].y, vl1[it].z, vl1[it].w};
#pragma unroll
        for (int j = 0; j < 8; ++j) {
            int f = oct * 8 + j;
            unsigned int lo = (aw[j >> 1] >> ((j & 1) * 16)) & 0xffffu;
            unsigned int hh = (bw[j >> 1] >> ((j & 1) * 16)) & 0xffffu;
            U[f * 100 + ((((c0 >> 3) ^ (f & 7))) << 2) + ((c0 & 7) >> 1)] = lo | (hh << 16);
        }
    }
    // ---- P[q][c] bf16 into U[PBASE..): stride 100 words
    const int q = wv * 16 + lx;
#pragma unroll
    for (int ct = 0; ct < 12; ++ct) {
        U[PBASE + q * 100 + ct * 8 + hi * 2 + 0] = cvtpk(s[ct][0] * inv, s[ct][1] * inv);
        U[PBASE + q * 100 + ct * 8 + hi * 2 + 1] = cvtpk(s[ct][2] * inv, s[ct][3] * inv);
    }
    __syncthreads();

    // ---- PV: O^T[f][q] = V^T · P^T, single-MFMA bf16
    f32x4 o[4] = {{0.f,0.f,0.f,0.f},{0.f,0.f,0.f,0.f},{0.f,0.f,0.f,0.f},{0.f,0.f,0.f,0.f}};
    const unsigned short* Uh = (const unsigned short*)U;
#pragma unroll
    for (int ks = 0; ks < 6; ++ks) {
        short8 P8 = *(const short8*)(Uh + PBASE * 2 + q * 200 + ks * 32 + hi * 8);
#pragma unroll
        for (int ft = 0; ft < 4; ++ft) {
            int f = ft * 16 + lx;
            short8 V8 = *(const short8*)(Uh + f * 200 + ((((4 * ks + hi) ^ (f & 7))) << 3));
            o[ft] = __builtin_amdgcn_mfma_f32_16x16x32_bf16(V8, P8, o[ft], 0, 0, 0);
        }
    }
    const int tko = Tk[qw];
#pragma unroll
    for (int ft = 0; ft < 4; ++ft) {
        float4 w4 = make_float4(o[ft][0], o[ft][1], o[ft][2], o[ft][3]);
        *(float4*)(vog + ((size_t)sbase + tko) * 64 + ft * 16 + hi * 4) = w4;
    }
}

// ---------------------------------------------------------------------------
// Combine rounds -> packed split att (A of the Wo GEMM).
// ---------------------------------------------------------------------------
__global__ __launch_bounds__(256) void combine_kernel(const float* __restrict__ vog,
                                                      const float* __restrict__ lseg,
                                                      unsigned int* __restrict__ attpk) {
    const int gid = blockIdx.x * 256 + threadIdx.x;
    const int k = gid & 63;
    const int t = (gid >> 6) & 2047;
    const int bh = gid >> 17;
    const int b = bh >> 3, h = bh & 7;
    float l[4], vo[4];
#pragma unroll
    for (int r = 0; r < 4; ++r) {
        l[r] = lseg[(size_t)(bh * 4 + r) * 2048 + t];
        vo[r] = vog[((size_t)(bh * 4 + r) * 2048 + t) * 64 + k];
    }
    float m = fmaxf(fmaxf(l[0], l[1]), fmaxf(l[2], l[3]));
    float ss = expf(l[0] - m) + expf(l[1] - m) + expf(l[2] - m) + expf(l[3] - m);
    float lt = m + logf(ss);
    float out = 0.f;
#pragma unroll
    for (int r = 0; r < 4; ++r) out += expf(l[r] - lt) * vo[r];
    attpk[((size_t)(b * 2048 + t)) * 512 + h * 64 + k] = packsplit(out);
}

// ---------------------------------------------------------------------------
extern "C" void kernel_launch(void* const* d_in, const int* in_sizes, int n_in,
                              void* d_out, int out_size, void* d_ws, size_t ws_size,
                              hipStream_t stream) {
    const float* x  = (const float*)d_in[0];
    const float* Wq = (const float*)d_in[1];
    const float* bq = (const float*)d_in[2];
    const float* Wv = (const float*)d_in[3];
    const float* bv = (const float*)d_in[4];
    const float* Wo = (const float*)d_in[5];
    const float* bo = (const float*)d_in[6];
    const float* hv = (const float*)d_in[7];

    unsigned int* W = (unsigned int*)d_ws;
    float*          vog    = (float*)W;                         // [0, 8388608) f32
    float*          qkbuf  = (float*)W;                         // alias [0, 2097152) - dead after hash
    unsigned int*   xpk    = W + 2097152;                       // alias - dead after v-gemm
    unsigned int*   qkpk   = W + 8388608;                       // 2097152
    unsigned short* vpk    = (unsigned short*)(W + 10485760);   // 2097152 ushort (1M u32)
    unsigned int*   attpk  = W + 11534336;                      // 2097152
    float*          scaleQ = (float*)(W + 13631488);            // 32768
    int*            loc2   = (int*)(W + 13664256);              // 131072
    int*            stbuf  = (int*)(W + 13795328);              // 131072
    float*          lseg   = (float*)(W + 13926400);            // 131072
    unsigned int*   wvT    = W + 14057472;                      // 262144
    unsigned int*   woT    = W + 14319616;                      // 262144

    dim3 gg(64, 8), blk(256);
    pack_kernel<<<10240, 256, 0, stream>>>(x, Wv, Wo, xpk, wvT, woT);
    gemm_f32qk<<<gg, blk, 0, stream>>>(x, Wq, bq, qkbuf, qkpk, scaleQ);
    gemm_pk<<<gg, blk, 0, stream>>>(xpk, wvT, bv, (void*)vpk, 0);
    hash_kernel<<<512, 256, 0, stream>>>(qkbuf, hv, loc2);
    sort_kernel<<<64, 1024, 0, stream>>>(loc2, stbuf);
    attn_kernel<<<2048, 256, 0, stream>>>(qkpk, vpk, scaleQ, loc2, stbuf, lseg, vog);
    combine_kernel<<<8192, 256, 0, stream>>>(vog, lseg, attpk);
    gemm_pk<<<gg, blk, 0, stream>>>(attpk, woT, bo, d_out, 1);
}